// Round 12
// baseline (1608.756 us; speedup 1.0000x reference)
//
#include <hip/hip_runtime.h>
#include <hip/hip_bf16.h>

// Problem constants (fixed by the reference)
constexpr int DM = 768;     // d_model (GEMM K dim)
constexpr int NS = 24576;   // d_sae
constexpr int NB = 8192;    // batch
constexpr int K  = 64;      // top-k

constexpr int CAP   = 1024;  // per-row candidate capacity (expected ~462, +26 sigma)
constexpr int BANDC = 256;   // refinement band capacity
constexpr int RCAP  = 16;    // per-row per-block LDS bucket (expected 2.4; lossless overflow)
#define T0F   1.2f           // candidate pre-threshold (guarded; fallback if violated)
#define DELTA 0.015f         // selection uncertainty band >= 2*bf16-GEMM error (~0.007)

typedef __attribute__((ext_vector_type(8))) short short8v;
typedef __attribute__((ext_vector_type(4))) short short4v;
typedef __attribute__((ext_vector_type(4))) float f32x4;

__device__ __forceinline__ unsigned short f2bf(float f) {
    unsigned u = __float_as_uint(f);
    u += 0x7FFFu + ((u >> 16) & 1u);          // RNE, finite inputs only
    return (unsigned short)(u >> 16);
}
__device__ __forceinline__ float bf2f(unsigned short h) {
    return __uint_as_float(((unsigned)h) << 16);
}
__device__ __forceinline__ unsigned fkey(float f) {
    unsigned u = __float_as_uint(f);
    return (u & 0x80000000u) ? ~u : (u | 0x80000000u);   // monotonic ascending, all floats
}
__device__ __forceinline__ float key2f(unsigned k) {
    unsigned u = (k & 0x80000000u) ? (k & 0x7FFFFFFFu) : ~k;
    return __uint_as_float(u);
}

// ============ bf16 operand prep (fused A+B, one launch) ============
__global__ __launch_bounds__(256) void prep_bf(
    const float* __restrict__ x, const float* __restrict__ bp,
    const float* __restrict__ We, short* __restrict__ Ah, short* __restrict__ Bh)
{
    const int i = blockIdx.x * 256 + threadIdx.x;
    constexpr int NA = NB * 192;                 // A-region float4 count
    if (i < NA) {
        const int row = i / 192;
        const int c = (i % 192) * 4;
        const float4 xv = *(const float4*)&x[(size_t)row * DM + c];
        const float4 pv = *(const float4*)&bp[c];
        float a[4] = {xv.x - pv.x, xv.y - pv.y, xv.z - pv.z, xv.w - pv.w};
        short4v h;
        #pragma unroll
        for (int j = 0; j < 4; ++j) h[j] = (short)f2bf(a[j]);
        *(short4v*)&Ah[(size_t)row * DM + c] = h;
    } else {
        const int j2 = i - NA;
        const int row = j2 / 192;
        const int c = (j2 % 192) * 4;
        const float4 wv = *(const float4*)&We[(size_t)row * DM + c];
        float a[4] = {wv.x, wv.y, wv.z, wv.w};
        short4v h;
        #pragma unroll
        for (int j = 0; j < 4; ++j) h[j] = (short)f2bf(a[j]);
        *(short4v*)&Bh[(size_t)row * DM + c] = h;
    }
}

// ============ bf16 MFMA encode GEMM (register-direct, NO LDS in K-loop)
//              + per-row-bucket filter epilogue ============
// Rounds 7-11 established the LDS-staged K-loop is LDS-read-throughput bound
// (12 waves x 8 ds_read_b128 ~ 1130 cyc/CU/step vs 233 cyc MFMA). Both operand
// panels are L2/L3-resident (A 12.6 MB, B 37.7 MB < 256 MB L3), so fragments
// are loaded global->VGPR directly: per-lane addresses give full-cache-line
// utilization (16 rows x 64 B per 4-load group). K-loop fully unrolled ->
// immediate offsets, 2-stage register ping-pong, zero barriers.
__global__ __launch_bounds__(256) void encode_filter(
    const short* __restrict__ Ah, const short* __restrict__ Bh,
    const float* __restrict__ be,
    unsigned long long* __restrict__ cand, int* __restrict__ cnt)
{
    __shared__ unsigned long long lbuf[128 * RCAP];   // 16 KB per-row buckets
    __shared__ int lcnt[128];

    const int t = threadIdx.x;
    const int l = t & 63;
    const int w = t >> 6;           // wave 0..3 -> (wm,wn) in 2x2
    const int wm = w >> 1, wn = w & 1;
    const int bm = blockIdx.y * 128;
    const int bn = blockIdx.x * 128;

    const int lr = l & 15;          // fragment row within 16
    const int k8 = (l >> 4) * 8;    // fragment k offset (elements)

    if (t < 128) lcnt[t] = 0;

    // per-lane fragment base pointers (8 x 64-bit, computed once)
    const short* pa[4];
    const short* pb[4];
    #pragma unroll
    for (int m = 0; m < 4; ++m)
        pa[m] = Ah + (size_t)(bm + wm * 64 + m * 16 + lr) * DM + k8;
    #pragma unroll
    for (int n = 0; n < 4; ++n)
        pb[n] = Bh + (size_t)(bn + wn * 64 + n * 16 + lr) * DM + k8;

    f32x4 acc[4][4];
    #pragma unroll
    for (int m = 0; m < 4; ++m)
        #pragma unroll
        for (int n = 0; n < 4; ++n)
            acc[m][n] = f32x4{0.f, 0.f, 0.f, 0.f};

    short8v a0[4], b0[4], a1[4], b1[4];

#define LDF(A_, B_, KS)                                              \
    _Pragma("unroll")                                                \
    for (int m_ = 0; m_ < 4; ++m_) A_[m_] = *(const short8v*)(pa[m_] + (KS)); \
    _Pragma("unroll")                                                \
    for (int n_ = 0; n_ < 4; ++n_) B_[n_] = *(const short8v*)(pb[n_] + (KS));

#define MMA(A_, B_)                                                  \
    _Pragma("unroll")                                                \
    for (int m_ = 0; m_ < 4; ++m_)                                   \
        _Pragma("unroll")                                            \
        for (int n_ = 0; n_ < 4; ++n_)                               \
            acc[m_][n_] = __builtin_amdgcn_mfma_f32_16x16x32_bf16(A_[m_], B_[n_], acc[m_][n_], 0, 0, 0);

    LDF(a0, b0, 0);
    #pragma unroll
    for (int ks = 0; ks < DM; ks += 64) {       // 12 fully-unrolled iterations
        LDF(a1, b1, ks + 32);                   // next half-step's loads in flight
        MMA(a0, b0);
        if (ks + 64 < DM) { LDF(a0, b0, ks + 64); }
        MMA(a1, b1);
    }
#undef LDF
#undef MMA

    __syncthreads();                 // lcnt init visible to all waves

    // ---- stage 1: predicated per-row LDS bucket push ----
    // C/D layout: col = lane&15, row = (lane>>4)*4 + r
    #pragma unroll
    for (int n = 0; n < 4; ++n) {
        const int colg = bn + wn * 64 + n * 16 + lr;
        const float bev = be[colg];
        #pragma unroll
        for (int m = 0; m < 4; ++m) {
            const int rl0 = wm * 64 + m * 16 + (l >> 4) * 4;
            #pragma unroll
            for (int r = 0; r < 4; ++r) {
                const float v = acc[m][n][r] + bev;
                if (v >= T0F) {
                    const int rl = rl0 + r;
                    const unsigned long long e =
                        ((unsigned long long)__float_as_uint(v) << 32) | (unsigned)colg;
                    const int p = atomicAdd(&lcnt[rl], 1);
                    if (p < RCAP) {
                        lbuf[rl * RCAP + p] = e;
                    } else {
                        // lossless slow path on bucket overflow (rare)
                        const int q = atomicAdd(&cnt[bm + rl], 1);
                        if (q < CAP) cand[(size_t)(bm + rl) * CAP + q] = e;
                    }
                }
            }
        }
    }
    __syncthreads();

    // ---- stage 2: one global atomic per row, parallel copy ----
    if (t < 128) {
        int c = lcnt[t]; if (c > RCAP) c = RCAP;
        if (c > 0) {
            const int rowg = bm + t;
            const int base = atomicAdd(&cnt[rowg], c);
            for (int i = 0; i < c; ++i) {
                const int p = base + i;
                if (p < CAP) cand[(size_t)rowg * CAP + p] = lbuf[t * RCAP + i];
            }
        }
    }
}

// ============ fast top-k on candidate lists (LDS radix + exact band) ============
// z_sparse region is pre-zeroed by hipMemsetAsync: scatter-only here.
__global__ __launch_bounds__(256) void topk_fast(
    const unsigned long long* __restrict__ cand, const int* __restrict__ cnt,
    float* __restrict__ z,
    const float* __restrict__ x, const float* __restrict__ bp,
    const float* __restrict__ We, const float* __restrict__ be,
    float* __restrict__ tv, int* __restrict__ ti, int* __restrict__ rowflag)
{
    const int row = blockIdx.x;
    const int t = threadIdx.x;
    const int l = t & 63;
    const int w = t >> 6;
    float* zr = z + (size_t)row * NS;

    const int cc = cnt[row];
    if (cc < K || cc > CAP) { if (t == 0) rowflag[row] = 1; return; }

    __shared__ unsigned ckey[CAP];
    __shared__ int      cidx[CAP];
    __shared__ unsigned hist[256];
    __shared__ int   bandi[BANDC];
    __shared__ float bexa[BANDC];
    __shared__ int   cini[K];
    __shared__ float cinf[K];
    __shared__ int   seli[K];
    __shared__ float selv[K];
    __shared__ unsigned s_prefix, s_pmask;
    __shared__ int s_need, s_cin, s_bc, s_ns;

    const unsigned long long* cr = cand + (size_t)row * CAP;
    for (int i = t; i < cc; i += 256) {
        const unsigned long long pk = cr[i];
        ckey[i] = (unsigned)(pk >> 32);          // raw f32 bits; all >= T0F > 0 -> monotonic
        cidx[i] = (int)(unsigned)(pk & 0xFFFFFFFFull);
    }
    if (t == 0) { s_prefix = 0u; s_pmask = 0u; s_need = K; s_cin = 0; s_bc = 0; s_ns = 0; }
    __syncthreads();

    // exact radix select of rank-K key (4 x 8-bit passes, LDS only)
    for (int shift = 24; shift >= 0; shift -= 8) {
        hist[t] = 0u;
        __syncthreads();
        const unsigned prefix = s_prefix, pmask = s_pmask;
        for (int c = t; c < cc; c += 256) {
            const unsigned u = ckey[c];
            if ((u & pmask) == prefix) atomicAdd(&hist[(u >> shift) & 255u], 1u);
        }
        __syncthreads();
        if (t == 0) {
            int need = s_need; unsigned cum = 0; int sel = 0;
            for (int b = 255; b >= 0; --b) {
                if (cum + hist[b] >= (unsigned)need) { sel = b; break; }
                cum += hist[b];
            }
            s_need = need - (int)cum;
            s_prefix = prefix | ((unsigned)sel << shift);
            s_pmask = pmask | (0xFFu << shift);
        }
        __syncthreads();
    }

    const float Tf = __uint_as_float(s_prefix);
    if (Tf - DELTA < T0F) { if (t == 0) rowflag[row] = 1; return; }   // band dips under pre-threshold
    const unsigned khi = __float_as_uint(Tf + DELTA);
    const unsigned klo = __float_as_uint(Tf - DELTA);

    for (int c = t; c < cc; c += 256) {
        const unsigned u = ckey[c];
        if (u > khi) {                       // certainly in true top-K
            const int p = atomicAdd(&s_cin, 1);
            if (p < K) { cini[p] = cidx[c]; cinf[p] = __uint_as_float(u); }
        } else if (u >= klo) {               // boundary band: exact comparison needed
            const int p = atomicAdd(&s_bc, 1);
            if (p < BANDC) bandi[p] = cidx[c];
        }
    }
    __syncthreads();
    const int cin  = s_cin;
    const int bc   = s_bc;
    const int nsel = K - cin;
    if (cin >= K || bc > BANDC || bc < nsel) { if (t == 0) rowflag[row] = 1; return; }

    // exact fp32 dots for band members (one wave per member, round-robin)
    const float* xr = x + (size_t)row * DM;
    for (int c = w; c < bc; c += 4) {
        const int s = bandi[c];
        const float* wr = We + (size_t)s * DM;
        float acc = 0.f;
        for (int k = l; k < DM; k += 64)
            acc = fmaf(xr[k] - bp[k], wr[k], acc);
        #pragma unroll
        for (int off = 32; off > 0; off >>= 1) acc += __shfl_xor(acc, off);
        if (l == 0) bexa[c] = acc + be[s];
    }
    __syncthreads();

    // band ranking by (exact desc, index asc); take top nsel
    if (t < bc) {
        const float myv = bexa[t];
        const int myi = bandi[t];
        int rk = 0;
        for (int j = 0; j < bc; ++j) {
            const float vj = bexa[j];
            rk += (vj > myv) || (vj == myv && bandi[j] < myi);
        }
        if (rk < nsel) {
            const int p = atomicAdd(&s_ns, 1);
            if (p < K) { seli[p] = myi; selv[p] = myv; }
        }
    }
    if (t < cin) {
        const int p = atomicAdd(&s_ns, 1);
        if (p < K) { seli[p] = cini[t]; selv[p] = cinf[t]; }
    }
    __syncthreads();
    if (s_ns != K) { if (t == 0) rowflag[row] = 1; return; }
    if (t == 0) rowflag[row] = 0;

    // scatter selected (row pre-zeroed); slots rank-sorted by index -> deterministic
    if (t < K) {
        const int   myi = seli[t];
        const float myv = selv[t];
        int r = 0;
        #pragma unroll 8
        for (int j = 0; j < K; ++j) r += (seli[j] < myi);
        zr[myi] = myv;
        tv[(size_t)row * K + r] = myv;
        ti[(size_t)row * K + r] = myi;
    }
}

// ============ exact self-contained fallback (flagged rows only) ============
constexpr int XCAP = 6144;
#define XT0 0.8f

__global__ __launch_bounds__(256) void topk_exact_fb(
    float* __restrict__ z,
    const float* __restrict__ x, const float* __restrict__ bp,
    const float* __restrict__ We, const float* __restrict__ be,
    float* __restrict__ tv, int* __restrict__ ti, const int* __restrict__ rowflag)
{
    const int row = blockIdx.x;
    if (rowflag[row] == 0) return;
    const int t = threadIdx.x;
    float* zr = z + (size_t)row * NS;
    const float* xr = x + (size_t)row * DM;

    __shared__ unsigned xkey[XCAP];
    __shared__ int      xidx[XCAP];
    __shared__ unsigned hist[256];
    __shared__ int   eq[128];
    __shared__ float selv[K];
    __shared__ int   seli[K];
    __shared__ unsigned s_prefix, s_pmask;
    __shared__ int s_cnt, s_need, s_eqc, s_ns;

    if (t == 0) { s_cnt = 0; s_eqc = 0; s_ns = 0; s_prefix = 0u; s_pmask = 0u; s_need = K; }
    __syncthreads();

    // stage 1: exact recompute of row, collect values >= XT0
    for (int j = t; j < NS; j += 256) {
        const float* wr = We + (size_t)j * DM;
        float acc = 0.f;
        for (int k = 0; k < DM; ++k) acc = fmaf(xr[k] - bp[k], wr[k], acc);
        const float v = acc + be[j];
        if (v >= XT0) {
            const int p = atomicAdd(&s_cnt, 1);
            if (p < XCAP) { xkey[p] = fkey(v); xidx[p] = j; }
        }
    }
    __syncthreads();
    const int cc = s_cnt;

    if (cc >= K && cc <= XCAP) {
        // --- path A: radix on LDS list of exact values ---
        for (int shift = 24; shift >= 0; shift -= 8) {
            hist[t] = 0u;
            __syncthreads();
            const unsigned prefix = s_prefix, pmask = s_pmask;
            for (int c = t; c < cc; c += 256) {
                const unsigned u = xkey[c];
                if ((u & pmask) == prefix) atomicAdd(&hist[(u >> shift) & 255u], 1u);
            }
            __syncthreads();
            if (t == 0) {
                int need = s_need; unsigned cum = 0; int sel = 0;
                for (int b = 255; b >= 0; --b) {
                    if (cum + hist[b] >= (unsigned)need) { sel = b; break; }
                    cum += hist[b];
                }
                s_need = need - (int)cum;
                s_prefix = prefix | ((unsigned)sel << shift);
                s_pmask = pmask | (0xFFu << shift);
            }
            __syncthreads();
        }
        const unsigned T = s_prefix;
        const int need = s_need;

        for (int c = t; c < cc; c += 256)
            if (xkey[c] == T) { const int p = atomicAdd(&s_eqc, 1); if (p < 128) eq[p] = xidx[c]; }
        __syncthreads();
        if (t == 0) {   // keep `need` smallest tie indices
            int nn = s_eqc < 128 ? s_eqc : 128;
            int lim = need < nn ? need : nn;
            for (int a = 0; a < lim; ++a) {
                int mi = a;
                for (int b = a + 1; b < nn; ++b) if (eq[b] < eq[mi]) mi = b;
                int tmp = eq[a]; eq[a] = eq[mi]; eq[mi] = tmp;
            }
        }
        __syncthreads();

        for (int c = t; c < cc; c += 256) {
            const unsigned u = xkey[c];
            bool take = (u > T);
            if (u == T)
                for (int a = 0; a < need; ++a) if (eq[a] == xidx[c]) { take = true; break; }
            if (take) {
                const int p = atomicAdd(&s_ns, 1);
                if (p < K) { selv[p] = key2f(u); seli[p] = xidx[c]; }
            }
        }
        __syncthreads();
    } else {
        // --- path B: guaranteed full radix with per-pass recompute ---
        for (int shift = 24; shift >= 0; shift -= 8) {
            hist[t] = 0u;
            __syncthreads();
            const unsigned prefix = s_prefix, pmask = s_pmask;
            for (int j = t; j < NS; j += 256) {
                const float* wr = We + (size_t)j * DM;
                float acc = 0.f;
                for (int k = 0; k < DM; ++k) acc = fmaf(xr[k] - bp[k], wr[k], acc);
                const unsigned u = fkey(acc + be[j]);
                if ((u & pmask) == prefix) atomicAdd(&hist[(u >> shift) & 255u], 1u);
            }
            __syncthreads();
            if (t == 0) {
                int need = s_need; unsigned cum = 0; int sel = 0;
                for (int b = 255; b >= 0; --b) {
                    if (cum + hist[b] >= (unsigned)need) { sel = b; break; }
                    cum += hist[b];
                }
                s_need = need - (int)cum;
                s_prefix = prefix | ((unsigned)sel << shift);
                s_pmask = pmask | (0xFFu << shift);
            }
            __syncthreads();
        }
        const unsigned T = s_prefix;
        const int need = s_need;

        for (int j = t; j < NS; j += 256) {
            const float* wr = We + (size_t)j * DM;
            float acc = 0.f;
            for (int k = 0; k < DM; ++k) acc = fmaf(xr[k] - bp[k], wr[k], acc);
            if (fkey(acc + be[j]) == T) { const int p = atomicAdd(&s_eqc, 1); if (p < 128) eq[p] = j; }
        }
        __syncthreads();
        if (t == 0) {
            int nn = s_eqc < 128 ? s_eqc : 128;
            int lim = need < nn ? need : nn;
            for (int a = 0; a < lim; ++a) {
                int mi = a;
                for (int b = a + 1; b < nn; ++b) if (eq[b] < eq[mi]) mi = b;
                int tmp = eq[a]; eq[a] = eq[mi]; eq[mi] = tmp;
            }
        }
        __syncthreads();

        for (int j = t; j < NS; j += 256) {
            const float* wr = We + (size_t)j * DM;
            float acc = 0.f;
            for (int k = 0; k < DM; ++k) acc = fmaf(xr[k] - bp[k], wr[k], acc);
            const float v = acc + be[j];
            const unsigned u = fkey(v);
            bool take = (u > T);
            if (u == T)
                for (int a = 0; a < need; ++a) if (eq[a] == j) { take = true; break; }
            if (take) {
                const int p = atomicAdd(&s_ns, 1);
                if (p < K) { selv[p] = v; seli[p] = j; }
            }
        }
        __syncthreads();
    }

    // scatter + tv/ti (row pre-zeroed by memset; fast path wrote nothing here)
    const int ns = s_ns < K ? s_ns : K;
    if (t < ns) {
        const int   myi = seli[t];
        const float myv = selv[t];
        int r = 0;
        for (int j = 0; j < ns; ++j) r += (seli[j] < myi);
        zr[myi] = myv;
        tv[(size_t)row * K + r] = myv;
        ti[(size_t)row * K + r] = myi;
    }
}

// ============ W_dec transpose + bf16 convert: [768][24576] -> bf16 [24576][768] ============
__global__ __launch_bounds__(256) void transpose_wdec_bf(
    const float* __restrict__ W, unsigned short* __restrict__ WTb)
{
    __shared__ float tile[32][33];
    const int bx = blockIdx.x * 32;   // s
    const int by = blockIdx.y * 32;   // d
    const int tx = threadIdx.x & 31;
    const int ty = threadIdx.x >> 5;  // 0..7
    #pragma unroll
    for (int r = 0; r < 32; r += 8)
        tile[ty + r][tx] = W[(size_t)(by + ty + r) * NS + bx + tx];
    __syncthreads();
    #pragma unroll
    for (int r = 0; r < 32; r += 8)
        WTb[(size_t)(bx + ty + r) * DM + by + tx] = f2bf(tile[tx][ty + r]);
}

// ============ sparse decode (bf16 transposed weights, vectorized 8B/lane) ============
__global__ __launch_bounds__(192) void decode_bf(
    const float* __restrict__ tv, const int* __restrict__ ti,
    const unsigned short* __restrict__ WTb, const float* __restrict__ bd,
    float* __restrict__ recon)
{
    const int row = blockIdx.x;
    const int t = threadIdx.x;        // 192 threads, each owns 4 contiguous d
    __shared__ float sv[K];
    __shared__ int   si[K];
    if (t < K) { sv[t] = tv[(size_t)row * K + t]; si[t] = ti[(size_t)row * K + t]; }
    __syncthreads();
    const int d0 = t * 4;
    float4 a = *(const float4*)&bd[d0];
    #pragma unroll 4
    for (int k = 0; k < K; ++k) {
        const ushort4 wv = *(const ushort4*)(WTb + (size_t)si[k] * DM + d0);
        const float v = sv[k];
        a.x = fmaf(v, bf2f(wv.x), a.x);
        a.y = fmaf(v, bf2f(wv.y), a.y);
        a.z = fmaf(v, bf2f(wv.z), a.z);
        a.w = fmaf(v, bf2f(wv.w), a.w);
    }
    *(float4*)&recon[(size_t)row * DM + d0] = a;
}

// ===================== small-ws legacy path (round-1, validated) =====================
#define BM 128
#define BN 128
#define BK 16

__global__ __launch_bounds__(256) void encode_gemm(
    const float* __restrict__ x, const float* __restrict__ We,
    const float* __restrict__ be, const float* __restrict__ bp,
    float* __restrict__ z)
{
    __shared__ __align__(16) float As[BK][BM + 4];
    __shared__ __align__(16) float Bs[BK][BN + 4];

    const int t  = threadIdx.x;
    const int bm = blockIdx.y * BM;
    const int bn = blockIdx.x * BN;
    const int tm = (t / 16) * 8;
    const int tn = (t % 16) * 8;

    float acc[8][8] = {};

    for (int k0 = 0; k0 < DM; k0 += BK) {
        #pragma unroll
        for (int h = 0; h < 2; ++h) {
            const int q  = t + h * 256;
            const int m  = q >> 2;
            const int kq = (q & 3) * 4;
            const float4 av = *(const float4*)&x[(size_t)(bm + m) * DM + k0 + kq];
            const float4 pv = *(const float4*)&bp[k0 + kq];
            As[kq + 0][m] = av.x - pv.x;
            As[kq + 1][m] = av.y - pv.y;
            As[kq + 2][m] = av.z - pv.z;
            As[kq + 3][m] = av.w - pv.w;
            const float4 bv = *(const float4*)&We[(size_t)(bn + m) * DM + k0 + kq];
            Bs[kq + 0][m] = bv.x;
            Bs[kq + 1][m] = bv.y;
            Bs[kq + 2][m] = bv.z;
            Bs[kq + 3][m] = bv.w;
        }
        __syncthreads();

        #pragma unroll
        for (int kk = 0; kk < BK; ++kk) {
            float a[8], b[8];
            *(float4*)&a[0] = *(const float4*)&As[kk][tm];
            *(float4*)&a[4] = *(const float4*)&As[kk][tm + 4];
            *(float4*)&b[0] = *(const float4*)&Bs[kk][tn];
            *(float4*)&b[4] = *(const float4*)&Bs[kk][tn + 4];
            #pragma unroll
            for (int i = 0; i < 8; ++i)
                #pragma unroll
                for (int j = 0; j < 8; ++j)
                    acc[i][j] = fmaf(a[i], b[j], acc[i][j]);
        }
        __syncthreads();
    }

    float4 be0 = *(const float4*)&be[bn + tn];
    float4 be1 = *(const float4*)&be[bn + tn + 4];
    #pragma unroll
    for (int i = 0; i < 8; ++i) {
        const size_t rowoff = (size_t)(bm + tm + i) * NS + bn + tn;
        float4 c0, c1;
        c0.x = acc[i][0] + be0.x; c0.y = acc[i][1] + be0.y;
        c0.z = acc[i][2] + be0.z; c0.w = acc[i][3] + be0.w;
        c1.x = acc[i][4] + be1.x; c1.y = acc[i][5] + be1.y;
        c1.z = acc[i][6] + be1.z; c1.w = acc[i][7] + be1.w;
        *(float4*)&z[rowoff]     = c0;
        *(float4*)&z[rowoff + 4] = c1;
    }
}

__global__ __launch_bounds__(256) void topk_kernel(
    float* __restrict__ z, float* __restrict__ tv, int* __restrict__ ti)
{
    const int row = blockIdx.x;
    float* zr = z + (size_t)row * NS;
    const int t = threadIdx.x;

    __shared__ unsigned hist[256];
    __shared__ unsigned s_prefix, s_pmask;
    __shared__ int s_need;
    __shared__ int eqidx[128];
    __shared__ int eqcnt, outcnt;
    __shared__ float osv[K];
    __shared__ int   osi[K];

    if (t == 0) { s_prefix = 0u; s_pmask = 0u; s_need = K; eqcnt = 0; outcnt = 0; }
    __syncthreads();

    for (int shift = 24; shift >= 0; shift -= 8) {
        hist[t] = 0u;
        __syncthreads();
        const unsigned prefix = s_prefix, pmask = s_pmask;
        for (int i = t; i < NS; i += 256) {
            unsigned u = fkey(zr[i]);
            if ((u & pmask) == prefix) atomicAdd(&hist[(u >> shift) & 255u], 1u);
        }
        __syncthreads();
        if (t == 0) {
            int need = s_need;
            unsigned cum = 0; int sel = 0;
            for (int b = 255; b >= 0; --b) {
                if (cum + hist[b] >= (unsigned)need) { sel = b; break; }
                cum += hist[b];
            }
            s_need   = need - (int)cum;
            s_prefix = prefix | ((unsigned)sel << shift);
            s_pmask  = pmask | (0xFFu << shift);
        }
        __syncthreads();
    }

    const unsigned T = s_prefix;
    const int need = s_need;

    for (int i = t; i < NS; i += 256) {
        if (fkey(zr[i]) == T) {
            int p = atomicAdd(&eqcnt, 1);
            if (p < 128) eqidx[p] = i;
        }
    }
    __syncthreads();
    if (t == 0) {
        int nn = eqcnt < 128 ? eqcnt : 128;
        int lim = need < nn ? need : nn;
        for (int a = 0; a < lim; ++a) {
            int mi = a;
            for (int b = a + 1; b < nn; ++b) if (eqidx[b] < eqidx[mi]) mi = b;
            int tmp = eqidx[a]; eqidx[a] = eqidx[mi]; eqidx[mi] = tmp;
        }
    }
    __syncthreads();

    for (int i = t; i < NS; i += 256) {
        const float v = zr[i];
        const unsigned u = fkey(v);
        bool take = (u > T);
        if (u == T) {
            for (int a = 0; a < need; ++a) if (eqidx[a] == i) { take = true; break; }
        }
        if (take) {
            int p = atomicAdd(&outcnt, 1);
            if (p < K) { osv[p] = v; osi[p] = i; }
        } else {
            zr[i] = 0.0f;
        }
    }
    __syncthreads();

    if (tv != nullptr && t < K) {
        const int   myi = osi[t];
        const float myv = osv[t];
        int r = 0;
        #pragma unroll 8
        for (int j = 0; j < K; ++j) r += (osi[j] < myi);
        tv[(size_t)row * K + r] = myv;
        ti[(size_t)row * K + r] = myi;
    }
}

__global__ __launch_bounds__(256) void decode_nt(
    const float* __restrict__ tv, const int* __restrict__ ti,
    const float* __restrict__ Wd, const float* __restrict__ bd,
    float* __restrict__ recon)
{
    const int row = blockIdx.x;
    const int t = threadIdx.x;
    __shared__ float sv[K];
    __shared__ int   si[K];
    if (t < K) { sv[t] = tv[(size_t)row * K + t]; si[t] = ti[(size_t)row * K + t]; }
    __syncthreads();
    float a0 = bd[t], a1 = bd[t + 256], a2 = bd[t + 512];
    for (int k = 0; k < K; ++k) {
        const float v = sv[k];
        const int s = si[k];
        a0 = fmaf(v, Wd[(size_t)t * NS + s],         a0);
        a1 = fmaf(v, Wd[(size_t)(t + 256) * NS + s], a1);
        a2 = fmaf(v, Wd[(size_t)(t + 512) * NS + s], a2);
    }
    float* rr = recon + (size_t)row * DM;
    rr[t] = a0; rr[t + 256] = a1; rr[t + 512] = a2;
}

__global__ __launch_bounds__(256) void decode_scan(
    const float* __restrict__ z, const float* __restrict__ Wd,
    const float* __restrict__ bd, float* __restrict__ recon)
{
    constexpr int CAP2 = 96;
    const int row = blockIdx.x;
    const int t = threadIdx.x;
    __shared__ float sv[CAP2], sv2[CAP2];
    __shared__ int   si[CAP2], si2[CAP2];
    __shared__ int cnt;
    if (t == 0) cnt = 0;
    __syncthreads();
    const float* zr = z + (size_t)row * NS;
    for (int i = t; i < NS; i += 256) {
        float v = zr[i];
        if (v != 0.0f) { int p = atomicAdd(&cnt, 1); if (p < CAP2) { sv[p] = v; si[p] = i; } }
    }
    __syncthreads();
    const int n = cnt < CAP2 ? cnt : CAP2;
    if (t < n) {
        int myi = si[t]; int r = 0;
        for (int j = 0; j < n; ++j) r += (si[j] < myi);
        sv2[r] = sv[t]; si2[r] = myi;
    }
    __syncthreads();
    float a0 = bd[t], a1 = bd[t + 256], a2 = bd[t + 512];
    for (int k = 0; k < n; ++k) {
        const float v = sv2[k];
        const int s = si2[k];
        a0 = fmaf(v, Wd[(size_t)t * NS + s],         a0);
        a1 = fmaf(v, Wd[(size_t)(t + 256) * NS + s], a1);
        a2 = fmaf(v, Wd[(size_t)(t + 512) * NS + s], a2);
    }
    float* rr = recon + (size_t)row * DM;
    rr[t] = a0; rr[t + 256] = a1; rr[t + 512] = a2;
}

// ===================== launch =====================
extern "C" void kernel_launch(void* const* d_in, const int* in_sizes, int n_in,
                              void* d_out, int out_size, void* d_ws, size_t ws_size,
                              hipStream_t stream) {
    const float* x  = (const float*)d_in[0];
    const float* We = (const float*)d_in[1];
    const float* be = (const float*)d_in[2];
    const float* Wd = (const float*)d_in[3];
    const float* bd = (const float*)d_in[4];
    const float* bp = (const float*)d_in[5];

    float* recon = (float*)d_out;                       // [8192][768]
    float* zs    = recon + (size_t)NB * DM;             // [8192][24576] (z_sparse)

    const size_t szAh   = (size_t)NB * DM * 2;          // 12.6 MB
    const size_t szBh   = (size_t)NS * DM * 2;          // 37.7 MB  (Ah|Bh reused as WTb: 37.7 <= 50.3)
    const size_t szCand = (size_t)NB * CAP * 8;         // 67.1 MB
    const size_t szCnt  = (size_t)NB * 4;               // 32 KB
    const size_t szTV   = (size_t)NB * K * 4;           // 2 MB
    const size_t szTI   = (size_t)NB * K * 4;           // 2 MB
    const size_t szFL   = (size_t)NB * 4;               // 32 KB
    const size_t need_fast = szAh + szBh + szCand + szCnt + szTV + szTI + szFL;  // ~122 MB

    if (ws_size >= need_fast) {
        char* p = (char*)d_ws;
        short* Ah = (short*)p;                         p += szAh;
        short* Bh = (short*)p;                         p += szBh;
        unsigned long long* cand = (unsigned long long*)p;  p += szCand;
        int*   cnt = (int*)p;                          p += szCnt;
        float* tv  = (float*)p;                        p += szTV;
        int*   ti  = (int*)p;                          p += szTI;
        int*   fl  = (int*)p;
        unsigned short* WTb = (unsigned short*)d_ws;   // aliases Ah|Bh after encode

        hipMemsetAsync(zs, 0, (size_t)NB * NS * 4, stream);   // fill engine: z_sparse zeros
        hipMemsetAsync(cnt, 0, szCnt, stream);
        prep_bf<<<(NB * 192 + NS * 192) / 256, 256, 0, stream>>>(x, bp, We, Ah, Bh);
        encode_filter<<<dim3(NS / 128, NB / 128), 256, 0, stream>>>(Ah, Bh, be, cand, cnt);
        transpose_wdec_bf<<<dim3(NS / 32, DM / 32), 256, 0, stream>>>(Wd, WTb);  // overwrites Ah|Bh
        topk_fast<<<NB, 256, 0, stream>>>(cand, cnt, zs, x, bp, We, be, tv, ti, fl);
        topk_exact_fb<<<NB, 256, 0, stream>>>(zs, x, bp, We, be, tv, ti, fl);
        decode_bf<<<NB, 192, 0, stream>>>(tv, ti, WTb, bd, recon);
    } else {
        const size_t need_small = szTV + szTI;
        float* tv = (float*)d_ws;
        int*   ti = (int*)((char*)d_ws + szTV);

        dim3 gg(NS / BN, NB / BM);
        encode_gemm<<<gg, 256, 0, stream>>>(x, We, be, bp, zs);

        if (ws_size >= need_small) {
            topk_kernel<<<NB, 256, 0, stream>>>(zs, tv, ti);
            decode_nt<<<NB, 256, 0, stream>>>(tv, ti, Wd, bd, recon);
        } else {
            topk_kernel<<<NB, 256, 0, stream>>>(zs, nullptr, nullptr);
            decode_scan<<<NB, 256, 0, stream>>>(zs, Wd, bd, recon);
        }
    }
}

// Round 13
// 965.135 us; speedup vs baseline: 1.6669x; 1.6669x over previous
//
#include <hip/hip_runtime.h>
#include <hip/hip_bf16.h>

// Problem constants (fixed by the reference)
constexpr int DM = 768;     // d_model (GEMM K dim)
constexpr int NS = 24576;   // d_sae
constexpr int NB = 8192;    // batch
constexpr int K  = 64;      // top-k

constexpr int CAP   = 1024;  // per-row candidate capacity (expected ~462, +26 sigma)
constexpr int BANDC = 256;   // refinement band capacity
constexpr int RCAP  = 16;    // per-row per-block LDS bucket (expected 2.4; lossless overflow)
#define T0F   1.2f           // candidate pre-threshold (guarded; fallback if violated)
#define DELTA 0.015f         // selection uncertainty band >= 2*bf16-GEMM error (~0.007)

typedef __attribute__((ext_vector_type(8))) short short8v;
typedef __attribute__((ext_vector_type(4))) short short4v;
typedef __attribute__((ext_vector_type(4))) float f32x4;

__device__ __forceinline__ unsigned short f2bf(float f) {
    unsigned u = __float_as_uint(f);
    u += 0x7FFFu + ((u >> 16) & 1u);          // RNE, finite inputs only
    return (unsigned short)(u >> 16);
}
__device__ __forceinline__ float bf2f(unsigned short h) {
    return __uint_as_float(((unsigned)h) << 16);
}
__device__ __forceinline__ unsigned fkey(float f) {
    unsigned u = __float_as_uint(f);
    return (u & 0x80000000u) ? ~u : (u | 0x80000000u);   // monotonic ascending, all floats
}
__device__ __forceinline__ float key2f(unsigned k) {
    unsigned u = (k & 0x80000000u) ? (k & 0x7FFFFFFFu) : ~k;
    return __uint_as_float(u);
}

// ============ fused prep: bf16 A+B convert AND W_dec transpose (one launch) ============
constexpr int PREP_BLKS = (NB * 192 + NS * 192) / 256;   // 24576
constexpr int TR_BLKS   = (NS / 32) * (DM / 32);         // 18432

__global__ __launch_bounds__(256) void prep_all(
    const float* __restrict__ x, const float* __restrict__ bp,
    const float* __restrict__ We, short* __restrict__ Ah, short* __restrict__ Bh,
    const float* __restrict__ Wd, unsigned short* __restrict__ WTb)
{
    __shared__ float tile[32][33];
    const int blk = blockIdx.x;
    if (blk < PREP_BLKS) {
        const int i = blk * 256 + threadIdx.x;
        constexpr int NA = NB * 192;                 // A-region float4 count
        if (i < NA) {
            const int row = i / 192;
            const int c = (i % 192) * 4;
            const float4 xv = *(const float4*)&x[(size_t)row * DM + c];
            const float4 pv = *(const float4*)&bp[c];
            float a[4] = {xv.x - pv.x, xv.y - pv.y, xv.z - pv.z, xv.w - pv.w};
            short4v h;
            #pragma unroll
            for (int j = 0; j < 4; ++j) h[j] = (short)f2bf(a[j]);
            *(short4v*)&Ah[(size_t)row * DM + c] = h;
        } else {
            const int j2 = i - NA;
            const int row = j2 / 192;
            const int c = (j2 % 192) * 4;
            const float4 wv = *(const float4*)&We[(size_t)row * DM + c];
            float a[4] = {wv.x, wv.y, wv.z, wv.w};
            short4v h;
            #pragma unroll
            for (int j = 0; j < 4; ++j) h[j] = (short)f2bf(a[j]);
            *(short4v*)&Bh[(size_t)row * DM + c] = h;
        }
    } else {
        const int i2 = blk - PREP_BLKS;
        const int bx = (i2 % (NS / 32)) * 32;   // s
        const int by = (i2 / (NS / 32)) * 32;   // d
        const int tx = threadIdx.x & 31;
        const int ty = threadIdx.x >> 5;        // 0..7
        #pragma unroll
        for (int r = 0; r < 32; r += 8)
            tile[ty + r][tx] = Wd[(size_t)(by + ty + r) * NS + bx + tx];
        __syncthreads();
        #pragma unroll
        for (int r = 0; r < 32; r += 8)
            WTb[(size_t)(bx + ty + r) * DM + by + tx] = f2bf(tile[tx][ty + r]);
    }
}

// ============ bf16 MFMA encode GEMM + per-row-bucket filter epilogue ============
// Round-8 proven structure, with TWO K-steps per barrier pair (4 x 16 KB buffer
// sets, identical per-buffer layout+swizzle as the validated single-set code).
// Halves the vmcnt-drain barrier count (24 pairs -> 12). lbuf aliases set 0.
__global__ __launch_bounds__(256) void encode_filter(
    const short* __restrict__ Ah, const short* __restrict__ Bh,
    const float* __restrict__ be,
    unsigned long long* __restrict__ cand, int* __restrict__ cnt)
{
    __shared__ __align__(16) char smem[32768];   // A0|B0|A1|B1, 8 KB each
    unsigned long long* lbuf = (unsigned long long*)smem;   // 16 KB, aliases A0|B0 after loop
    __shared__ int lcnt[128];

    const int t = threadIdx.x;
    const int l = t & 63;
    const int w = t >> 6;           // wave 0..3 -> (wm,wn) in 2x2
    const int wm = w >> 1, wn = w & 1;
    const int bm = blockIdx.y * 128;
    const int bn = blockIdx.x * 128;

    const int srow = l >> 2;                              // staging: row within 16-row chunk
    const int gsrc = (((l & 3) ^ ((l >> 2) & 3)) * 8);    // staging k-granule swizzle (r8-verified)
    const int lr = l & 15;
    const int gs8 = (((l >> 4) ^ (l & 3)) * 8);           // matching read granule

    f32x4 acc[4][4];
    #pragma unroll
    for (int m = 0; m < 4; ++m)
        #pragma unroll
        for (int n = 0; n < 4; ++n)
            acc[m][n] = f32x4{0.f, 0.f, 0.f, 0.f};

    for (int ks = 0; ks < DM; ks += 64) {
        __syncthreads();
        // stage both half-steps into independent buffer sets
        #pragma unroll
        for (int s = 0; s < 2; ++s) {
            short* As = (short*)(smem + s * 16384);
            short* Bs = (short*)(smem + s * 16384 + 8192);
            const int kss = ks + s * 32;
            #pragma unroll
            for (int h = 0; h < 2; ++h) {
                const int c = w * 2 + h;            // chunk 0..7 (wave-uniform)
                const int row = c * 16 + srow;      // tile row 0..127
                __builtin_amdgcn_global_load_lds(
                    (const __attribute__((address_space(1))) void*)(Ah + (size_t)(bm + row) * DM + kss + gsrc),
                    (__attribute__((address_space(3))) void*)(As + c * 512), 16, 0, 0);
                __builtin_amdgcn_global_load_lds(
                    (const __attribute__((address_space(1))) void*)(Bh + (size_t)(bn + row) * DM + kss + gsrc),
                    (__attribute__((address_space(3))) void*)(Bs + c * 512), 16, 0, 0);
            }
        }
        __syncthreads();   // drains all 8 loads; both sets ready

        #pragma unroll
        for (int s = 0; s < 2; ++s) {
            const short* As = (const short*)(smem + s * 16384);
            const short* Bs = (const short*)(smem + s * 16384 + 8192);
            short8v a[4], b[4];
            #pragma unroll
            for (int m = 0; m < 4; ++m)
                a[m] = *(const short8v*)&As[(wm * 64 + m * 16 + lr) * 32 + gs8];
            #pragma unroll
            for (int n = 0; n < 4; ++n)
                b[n] = *(const short8v*)&Bs[(wn * 64 + n * 16 + lr) * 32 + gs8];
            #pragma unroll
            for (int m = 0; m < 4; ++m)
                #pragma unroll
                for (int n = 0; n < 4; ++n)
                    acc[m][n] = __builtin_amdgcn_mfma_f32_16x16x32_bf16(a[m], b[n], acc[m][n], 0, 0, 0);
        }
    }

    // staging buffers now dead: hand the LDS to the buckets
    __syncthreads();                 // all waves' frag reads retired
    if (t < 128) lcnt[t] = 0;
    __syncthreads();                 // lcnt visible; lbuf alias safe

    // ---- stage 1: predicated per-row LDS bucket push ----
    // C/D layout: col = lane&15, row = (lane>>4)*4 + r
    #pragma unroll
    for (int n = 0; n < 4; ++n) {
        const int colg = bn + wn * 64 + n * 16 + lr;
        const float bev = be[colg];
        #pragma unroll
        for (int m = 0; m < 4; ++m) {
            const int rl0 = wm * 64 + m * 16 + (l >> 4) * 4;
            #pragma unroll
            for (int r = 0; r < 4; ++r) {
                const float v = acc[m][n][r] + bev;
                if (v >= T0F) {
                    const int rl = rl0 + r;
                    const unsigned long long e =
                        ((unsigned long long)__float_as_uint(v) << 32) | (unsigned)colg;
                    const int p = atomicAdd(&lcnt[rl], 1);
                    if (p < RCAP) {
                        lbuf[rl * RCAP + p] = e;
                    } else {
                        // lossless slow path on bucket overflow (rare)
                        const int q = atomicAdd(&cnt[bm + rl], 1);
                        if (q < CAP) cand[(size_t)(bm + rl) * CAP + q] = e;
                    }
                }
            }
        }
    }
    __syncthreads();

    // ---- stage 2: one global atomic per row, parallel copy ----
    if (t < 128) {
        int c = lcnt[t]; if (c > RCAP) c = RCAP;
        if (c > 0) {
            const int rowg = bm + t;
            const int base = atomicAdd(&cnt[rowg], c);
            for (int i = 0; i < c; ++i) {
                const int p = base + i;
                if (p < CAP) cand[(size_t)rowg * CAP + p] = lbuf[t * RCAP + i];
            }
        }
    }
}

// ============ fast top-k on candidate lists (LDS radix + exact band) ============
// z_sparse region is pre-zeroed by hipMemsetAsync: scatter-only here.
__global__ __launch_bounds__(256) void topk_fast(
    const unsigned long long* __restrict__ cand, const int* __restrict__ cnt,
    float* __restrict__ z,
    const float* __restrict__ x, const float* __restrict__ bp,
    const float* __restrict__ We, const float* __restrict__ be,
    float* __restrict__ tv, int* __restrict__ ti, int* __restrict__ rowflag)
{
    const int row = blockIdx.x;
    const int t = threadIdx.x;
    const int l = t & 63;
    const int w = t >> 6;
    float* zr = z + (size_t)row * NS;

    const int cc = cnt[row];
    if (cc < K || cc > CAP) { if (t == 0) rowflag[row] = 1; return; }

    __shared__ unsigned ckey[CAP];
    __shared__ int      cidx[CAP];
    __shared__ unsigned hist[256];
    __shared__ int   bandi[BANDC];
    __shared__ float bexa[BANDC];
    __shared__ int   cini[K];
    __shared__ float cinf[K];
    __shared__ int   seli[K];
    __shared__ float selv[K];
    __shared__ unsigned s_prefix, s_pmask;
    __shared__ int s_need, s_cin, s_bc, s_ns;

    const unsigned long long* cr = cand + (size_t)row * CAP;
    for (int i = t; i < cc; i += 256) {
        const unsigned long long pk = cr[i];
        ckey[i] = (unsigned)(pk >> 32);          // raw f32 bits; all >= T0F > 0 -> monotonic
        cidx[i] = (int)(unsigned)(pk & 0xFFFFFFFFull);
    }
    if (t == 0) { s_prefix = 0u; s_pmask = 0u; s_need = K; s_cin = 0; s_bc = 0; s_ns = 0; }
    __syncthreads();

    // exact radix select of rank-K key (4 x 8-bit passes, LDS only)
    for (int shift = 24; shift >= 0; shift -= 8) {
        hist[t] = 0u;
        __syncthreads();
        const unsigned prefix = s_prefix, pmask = s_pmask;
        for (int c = t; c < cc; c += 256) {
            const unsigned u = ckey[c];
            if ((u & pmask) == prefix) atomicAdd(&hist[(u >> shift) & 255u], 1u);
        }
        __syncthreads();
        if (t == 0) {
            int need = s_need; unsigned cum = 0; int sel = 0;
            for (int b = 255; b >= 0; --b) {
                if (cum + hist[b] >= (unsigned)need) { sel = b; break; }
                cum += hist[b];
            }
            s_need = need - (int)cum;
            s_prefix = prefix | ((unsigned)sel << shift);
            s_pmask = pmask | (0xFFu << shift);
        }
        __syncthreads();
    }

    const float Tf = __uint_as_float(s_prefix);
    if (Tf - DELTA < T0F) { if (t == 0) rowflag[row] = 1; return; }   // band dips under pre-threshold
    const unsigned khi = __float_as_uint(Tf + DELTA);
    const unsigned klo = __float_as_uint(Tf - DELTA);

    for (int c = t; c < cc; c += 256) {
        const unsigned u = ckey[c];
        if (u > khi) {                       // certainly in true top-K
            const int p = atomicAdd(&s_cin, 1);
            if (p < K) { cini[p] = cidx[c]; cinf[p] = __uint_as_float(u); }
        } else if (u >= klo) {               // boundary band: exact comparison needed
            const int p = atomicAdd(&s_bc, 1);
            if (p < BANDC) bandi[p] = cidx[c];
        }
    }
    __syncthreads();
    const int cin  = s_cin;
    const int bc   = s_bc;
    const int nsel = K - cin;
    if (cin >= K || bc > BANDC || bc < nsel) { if (t == 0) rowflag[row] = 1; return; }

    // exact fp32 dots for band members (one wave per member, round-robin)
    const float* xr = x + (size_t)row * DM;
    for (int c = w; c < bc; c += 4) {
        const int s = bandi[c];
        const float* wr = We + (size_t)s * DM;
        float acc = 0.f;
        for (int k = l; k < DM; k += 64)
            acc = fmaf(xr[k] - bp[k], wr[k], acc);
        #pragma unroll
        for (int off = 32; off > 0; off >>= 1) acc += __shfl_xor(acc, off);
        if (l == 0) bexa[c] = acc + be[s];
    }
    __syncthreads();

    // band ranking by (exact desc, index asc); take top nsel
    if (t < bc) {
        const float myv = bexa[t];
        const int myi = bandi[t];
        int rk = 0;
        for (int j = 0; j < bc; ++j) {
            const float vj = bexa[j];
            rk += (vj > myv) || (vj == myv && bandi[j] < myi);
        }
        if (rk < nsel) {
            const int p = atomicAdd(&s_ns, 1);
            if (p < K) { seli[p] = myi; selv[p] = myv; }
        }
    }
    if (t < cin) {
        const int p = atomicAdd(&s_ns, 1);
        if (p < K) { seli[p] = cini[t]; selv[p] = cinf[t]; }
    }
    __syncthreads();
    if (s_ns != K) { if (t == 0) rowflag[row] = 1; return; }
    if (t == 0) rowflag[row] = 0;

    // scatter selected (row pre-zeroed); slots rank-sorted by index -> deterministic
    if (t < K) {
        const int   myi = seli[t];
        const float myv = selv[t];
        int r = 0;
        #pragma unroll 8
        for (int j = 0; j < K; ++j) r += (seli[j] < myi);
        zr[myi] = myv;
        tv[(size_t)row * K + r] = myv;
        ti[(size_t)row * K + r] = myi;
    }
}

// ============ exact self-contained fallback (flagged rows only) ============
constexpr int XCAP = 6144;
#define XT0 0.8f

__global__ __launch_bounds__(256) void topk_exact_fb(
    float* __restrict__ z,
    const float* __restrict__ x, const float* __restrict__ bp,
    const float* __restrict__ We, const float* __restrict__ be,
    float* __restrict__ tv, int* __restrict__ ti, const int* __restrict__ rowflag)
{
    const int row = blockIdx.x;
    if (rowflag[row] == 0) return;
    const int t = threadIdx.x;
    float* zr = z + (size_t)row * NS;
    const float* xr = x + (size_t)row * DM;

    __shared__ unsigned xkey[XCAP];
    __shared__ int      xidx[XCAP];
    __shared__ unsigned hist[256];
    __shared__ int   eq[128];
    __shared__ float selv[K];
    __shared__ int   seli[K];
    __shared__ unsigned s_prefix, s_pmask;
    __shared__ int s_cnt, s_need, s_eqc, s_ns;

    if (t == 0) { s_cnt = 0; s_eqc = 0; s_ns = 0; s_prefix = 0u; s_pmask = 0u; s_need = K; }
    __syncthreads();

    // stage 1: exact recompute of row, collect values >= XT0
    for (int j = t; j < NS; j += 256) {
        const float* wr = We + (size_t)j * DM;
        float acc = 0.f;
        for (int k = 0; k < DM; ++k) acc = fmaf(xr[k] - bp[k], wr[k], acc);
        const float v = acc + be[j];
        if (v >= XT0) {
            const int p = atomicAdd(&s_cnt, 1);
            if (p < XCAP) { xkey[p] = fkey(v); xidx[p] = j; }
        }
    }
    __syncthreads();
    const int cc = s_cnt;

    if (cc >= K && cc <= XCAP) {
        // --- path A: radix on LDS list of exact values ---
        for (int shift = 24; shift >= 0; shift -= 8) {
            hist[t] = 0u;
            __syncthreads();
            const unsigned prefix = s_prefix, pmask = s_pmask;
            for (int c = t; c < cc; c += 256) {
                const unsigned u = xkey[c];
                if ((u & pmask) == prefix) atomicAdd(&hist[(u >> shift) & 255u], 1u);
            }
            __syncthreads();
            if (t == 0) {
                int need = s_need; unsigned cum = 0; int sel = 0;
                for (int b = 255; b >= 0; --b) {
                    if (cum + hist[b] >= (unsigned)need) { sel = b; break; }
                    cum += hist[b];
                }
                s_need = need - (int)cum;
                s_prefix = prefix | ((unsigned)sel << shift);
                s_pmask = pmask | (0xFFu << shift);
            }
            __syncthreads();
        }
        const unsigned T = s_prefix;
        const int need = s_need;

        for (int c = t; c < cc; c += 256)
            if (xkey[c] == T) { const int p = atomicAdd(&s_eqc, 1); if (p < 128) eq[p] = xidx[c]; }
        __syncthreads();
        if (t == 0) {   // keep `need` smallest tie indices
            int nn = s_eqc < 128 ? s_eqc : 128;
            int lim = need < nn ? need : nn;
            for (int a = 0; a < lim; ++a) {
                int mi = a;
                for (int b = a + 1; b < nn; ++b) if (eq[b] < eq[mi]) mi = b;
                int tmp = eq[a]; eq[a] = eq[mi]; eq[mi] = tmp;
            }
        }
        __syncthreads();

        for (int c = t; c < cc; c += 256) {
            const unsigned u = xkey[c];
            bool take = (u > T);
            if (u == T)
                for (int a = 0; a < need; ++a) if (eq[a] == xidx[c]) { take = true; break; }
            if (take) {
                const int p = atomicAdd(&s_ns, 1);
                if (p < K) { selv[p] = key2f(u); seli[p] = xidx[c]; }
            }
        }
        __syncthreads();
    } else {
        // --- path B: guaranteed full radix with per-pass recompute ---
        for (int shift = 24; shift >= 0; shift -= 8) {
            hist[t] = 0u;
            __syncthreads();
            const unsigned prefix = s_prefix, pmask = s_pmask;
            for (int j = t; j < NS; j += 256) {
                const float* wr = We + (size_t)j * DM;
                float acc = 0.f;
                for (int k = 0; k < DM; ++k) acc = fmaf(xr[k] - bp[k], wr[k], acc);
                const unsigned u = fkey(acc + be[j]);
                if ((u & pmask) == prefix) atomicAdd(&hist[(u >> shift) & 255u], 1u);
            }
            __syncthreads();
            if (t == 0) {
                int need = s_need; unsigned cum = 0; int sel = 0;
                for (int b = 255; b >= 0; --b) {
                    if (cum + hist[b] >= (unsigned)need) { sel = b; break; }
                    cum += hist[b];
                }
                s_need = need - (int)cum;
                s_prefix = prefix | ((unsigned)sel << shift);
                s_pmask = pmask | (0xFFu << shift);
            }
            __syncthreads();
        }
        const unsigned T = s_prefix;
        const int need = s_need;

        for (int j = t; j < NS; j += 256) {
            const float* wr = We + (size_t)j * DM;
            float acc = 0.f;
            for (int k = 0; k < DM; ++k) acc = fmaf(xr[k] - bp[k], wr[k], acc);
            if (fkey(acc + be[j]) == T) { const int p = atomicAdd(&s_eqc, 1); if (p < 128) eq[p] = j; }
        }
        __syncthreads();
        if (t == 0) {
            int nn = s_eqc < 128 ? s_eqc : 128;
            int lim = need < nn ? need : nn;
            for (int a = 0; a < lim; ++a) {
                int mi = a;
                for (int b = a + 1; b < nn; ++b) if (eq[b] < eq[mi]) mi = b;
                int tmp = eq[a]; eq[a] = eq[mi]; eq[mi] = tmp;
            }
        }
        __syncthreads();

        for (int j = t; j < NS; j += 256) {
            const float* wr = We + (size_t)j * DM;
            float acc = 0.f;
            for (int k = 0; k < DM; ++k) acc = fmaf(xr[k] - bp[k], wr[k], acc);
            const float v = acc + be[j];
            const unsigned u = fkey(v);
            bool take = (u > T);
            if (u == T)
                for (int a = 0; a < need; ++a) if (eq[a] == j) { take = true; break; }
            if (take) {
                const int p = atomicAdd(&s_ns, 1);
                if (p < K) { selv[p] = v; seli[p] = j; }
            }
        }
        __syncthreads();
    }

    // scatter + tv/ti (row pre-zeroed by memset; fast path wrote nothing here)
    const int ns = s_ns < K ? s_ns : K;
    if (t < ns) {
        const int   myi = seli[t];
        const float myv = selv[t];
        int r = 0;
        for (int j = 0; j < ns; ++j) r += (seli[j] < myi);
        zr[myi] = myv;
        tv[(size_t)row * K + r] = myv;
        ti[(size_t)row * K + r] = myi;
    }
}

// ============ sparse decode (bf16 transposed weights, vectorized 8B/lane) ============
__global__ __launch_bounds__(192) void decode_bf(
    const float* __restrict__ tv, const int* __restrict__ ti,
    const unsigned short* __restrict__ WTb, const float* __restrict__ bd,
    float* __restrict__ recon)
{
    const int row = blockIdx.x;
    const int t = threadIdx.x;        // 192 threads, each owns 4 contiguous d
    __shared__ float sv[K];
    __shared__ int   si[K];
    if (t < K) { sv[t] = tv[(size_t)row * K + t]; si[t] = ti[(size_t)row * K + t]; }
    __syncthreads();
    const int d0 = t * 4;
    float4 a = *(const float4*)&bd[d0];
    #pragma unroll 4
    for (int k = 0; k < K; ++k) {
        const ushort4 wv = *(const ushort4*)(WTb + (size_t)si[k] * DM + d0);
        const float v = sv[k];
        a.x = fmaf(v, bf2f(wv.x), a.x);
        a.y = fmaf(v, bf2f(wv.y), a.y);
        a.z = fmaf(v, bf2f(wv.z), a.z);
        a.w = fmaf(v, bf2f(wv.w), a.w);
    }
    *(float4*)&recon[(size_t)row * DM + d0] = a;
}

// ===================== small-ws legacy path (round-1, validated) =====================
#define BM 128
#define BN 128
#define BK 16

__global__ __launch_bounds__(256) void encode_gemm(
    const float* __restrict__ x, const float* __restrict__ We,
    const float* __restrict__ be, const float* __restrict__ bp,
    float* __restrict__ z)
{
    __shared__ __align__(16) float As[BK][BM + 4];
    __shared__ __align__(16) float Bs[BK][BN + 4];

    const int t  = threadIdx.x;
    const int bm = blockIdx.y * BM;
    const int bn = blockIdx.x * BN;
    const int tm = (t / 16) * 8;
    const int tn = (t % 16) * 8;

    float acc[8][8] = {};

    for (int k0 = 0; k0 < DM; k0 += BK) {
        #pragma unroll
        for (int h = 0; h < 2; ++h) {
            const int q  = t + h * 256;
            const int m  = q >> 2;
            const int kq = (q & 3) * 4;
            const float4 av = *(const float4*)&x[(size_t)(bm + m) * DM + k0 + kq];
            const float4 pv = *(const float4*)&bp[k0 + kq];
            As[kq + 0][m] = av.x - pv.x;
            As[kq + 1][m] = av.y - pv.y;
            As[kq + 2][m] = av.z - pv.z;
            As[kq + 3][m] = av.w - pv.w;
            const float4 bv = *(const float4*)&We[(size_t)(bn + m) * DM + k0 + kq];
            Bs[kq + 0][m] = bv.x;
            Bs[kq + 1][m] = bv.y;
            Bs[kq + 2][m] = bv.z;
            Bs[kq + 3][m] = bv.w;
        }
        __syncthreads();

        #pragma unroll
        for (int kk = 0; kk < BK; ++kk) {
            float a[8], b[8];
            *(float4*)&a[0] = *(const float4*)&As[kk][tm];
            *(float4*)&a[4] = *(const float4*)&As[kk][tm + 4];
            *(float4*)&b[0] = *(const float4*)&Bs[kk][tn];
            *(float4*)&b[4] = *(const float4*)&Bs[kk][tn + 4];
            #pragma unroll
            for (int i = 0; i < 8; ++i)
                #pragma unroll
                for (int j = 0; j < 8; ++j)
                    acc[i][j] = fmaf(a[i], b[j], acc[i][j]);
        }
        __syncthreads();
    }

    float4 be0 = *(const float4*)&be[bn + tn];
    float4 be1 = *(const float4*)&be[bn + tn + 4];
    #pragma unroll
    for (int i = 0; i < 8; ++i) {
        const size_t rowoff = (size_t)(bm + tm + i) * NS + bn + tn;
        float4 c0, c1;
        c0.x = acc[i][0] + be0.x; c0.y = acc[i][1] + be0.y;
        c0.z = acc[i][2] + be0.z; c0.w = acc[i][3] + be0.w;
        c1.x = acc[i][4] + be1.x; c1.y = acc[i][5] + be1.y;
        c1.z = acc[i][6] + be1.z; c1.w = acc[i][7] + be1.w;
        *(float4*)&z[rowoff]     = c0;
        *(float4*)&z[rowoff + 4] = c1;
    }
}

__global__ __launch_bounds__(256) void topk_kernel(
    float* __restrict__ z, float* __restrict__ tv, int* __restrict__ ti)
{
    const int row = blockIdx.x;
    float* zr = z + (size_t)row * NS;
    const int t = threadIdx.x;

    __shared__ unsigned hist[256];
    __shared__ unsigned s_prefix, s_pmask;
    __shared__ int s_need;
    __shared__ int eqidx[128];
    __shared__ int eqcnt, outcnt;
    __shared__ float osv[K];
    __shared__ int   osi[K];

    if (t == 0) { s_prefix = 0u; s_pmask = 0u; s_need = K; eqcnt = 0; outcnt = 0; }
    __syncthreads();

    for (int shift = 24; shift >= 0; shift -= 8) {
        hist[t] = 0u;
        __syncthreads();
        const unsigned prefix = s_prefix, pmask = s_pmask;
        for (int i = t; i < NS; i += 256) {
            unsigned u = fkey(zr[i]);
            if ((u & pmask) == prefix) atomicAdd(&hist[(u >> shift) & 255u], 1u);
        }
        __syncthreads();
        if (t == 0) {
            int need = s_need;
            unsigned cum = 0; int sel = 0;
            for (int b = 255; b >= 0; --b) {
                if (cum + hist[b] >= (unsigned)need) { sel = b; break; }
                cum += hist[b];
            }
            s_need   = need - (int)cum;
            s_prefix = prefix | ((unsigned)sel << shift);
            s_pmask  = pmask | (0xFFu << shift);
        }
        __syncthreads();
    }

    const unsigned T = s_prefix;
    const int need = s_need;

    for (int i = t; i < NS; i += 256) {
        if (fkey(zr[i]) == T) {
            int p = atomicAdd(&eqcnt, 1);
            if (p < 128) eqidx[p] = i;
        }
    }
    __syncthreads();
    if (t == 0) {
        int nn = eqcnt < 128 ? eqcnt : 128;
        int lim = need < nn ? need : nn;
        for (int a = 0; a < lim; ++a) {
            int mi = a;
            for (int b = a + 1; b < nn; ++b) if (eqidx[b] < eqidx[mi]) mi = b;
            int tmp = eqidx[a]; eqidx[a] = eqidx[mi]; eqidx[mi] = tmp;
        }
    }
    __syncthreads();

    for (int i = t; i < NS; i += 256) {
        const float v = zr[i];
        const unsigned u = fkey(v);
        bool take = (u > T);
        if (u == T) {
            for (int a = 0; a < need; ++a) if (eqidx[a] == i) { take = true; break; }
        }
        if (take) {
            int p = atomicAdd(&outcnt, 1);
            if (p < K) { osv[p] = v; osi[p] = i; }
        } else {
            zr[i] = 0.0f;
        }
    }
    __syncthreads();

    if (tv != nullptr && t < K) {
        const int   myi = osi[t];
        const float myv = osv[t];
        int r = 0;
        #pragma unroll 8
        for (int j = 0; j < K; ++j) r += (osi[j] < myi);
        tv[(size_t)row * K + r] = myv;
        ti[(size_t)row * K + r] = myi;
    }
}

__global__ __launch_bounds__(256) void decode_nt(
    const float* __restrict__ tv, const int* __restrict__ ti,
    const float* __restrict__ Wd, const float* __restrict__ bd,
    float* __restrict__ recon)
{
    const int row = blockIdx.x;
    const int t = threadIdx.x;
    __shared__ float sv[K];
    __shared__ int   si[K];
    if (t < K) { sv[t] = tv[(size_t)row * K + t]; si[t] = ti[(size_t)row * K + t]; }
    __syncthreads();
    float a0 = bd[t], a1 = bd[t + 256], a2 = bd[t + 512];
    for (int k = 0; k < K; ++k) {
        const float v = sv[k];
        const int s = si[k];
        a0 = fmaf(v, Wd[(size_t)t * NS + s],         a0);
        a1 = fmaf(v, Wd[(size_t)(t + 256) * NS + s], a1);
        a2 = fmaf(v, Wd[(size_t)(t + 512) * NS + s], a2);
    }
    float* rr = recon + (size_t)row * DM;
    rr[t] = a0; rr[t + 256] = a1; rr[t + 512] = a2;
}

__global__ __launch_bounds__(256) void decode_scan(
    const float* __restrict__ z, const float* __restrict__ Wd,
    const float* __restrict__ bd, float* __restrict__ recon)
{
    constexpr int CAP2 = 96;
    const int row = blockIdx.x;
    const int t = threadIdx.x;
    __shared__ float sv[CAP2], sv2[CAP2];
    __shared__ int   si[CAP2], si2[CAP2];
    __shared__ int cnt;
    if (t == 0) cnt = 0;
    __syncthreads();
    const float* zr = z + (size_t)row * NS;
    for (int i = t; i < NS; i += 256) {
        float v = zr[i];
        if (v != 0.0f) { int p = atomicAdd(&cnt, 1); if (p < CAP2) { sv[p] = v; si[p] = i; } }
    }
    __syncthreads();
    const int n = cnt < CAP2 ? cnt : CAP2;
    if (t < n) {
        int myi = si[t]; int r = 0;
        for (int j = 0; j < n; ++j) r += (si[j] < myi);
        sv2[r] = sv[t]; si2[r] = myi;
    }
    __syncthreads();
    float a0 = bd[t], a1 = bd[t + 256], a2 = bd[t + 512];
    for (int k = 0; k < n; ++k) {
        const float v = sv2[k];
        const int s = si2[k];
        a0 = fmaf(v, Wd[(size_t)t * NS + s],         a0);
        a1 = fmaf(v, Wd[(size_t)(t + 256) * NS + s], a1);
        a2 = fmaf(v, Wd[(size_t)(t + 512) * NS + s], a2);
    }
    float* rr = recon + (size_t)row * DM;
    rr[t] = a0; rr[t + 256] = a1; rr[t + 512] = a2;
}

// ===================== launch =====================
extern "C" void kernel_launch(void* const* d_in, const int* in_sizes, int n_in,
                              void* d_out, int out_size, void* d_ws, size_t ws_size,
                              hipStream_t stream) {
    const float* x  = (const float*)d_in[0];
    const float* We = (const float*)d_in[1];
    const float* be = (const float*)d_in[2];
    const float* Wd = (const float*)d_in[3];
    const float* bd = (const float*)d_in[4];
    const float* bp = (const float*)d_in[5];

    float* recon = (float*)d_out;                       // [8192][768]
    float* zs    = recon + (size_t)NB * DM;             // [8192][24576] (z_sparse)

    const size_t szAh   = (size_t)NB * DM * 2;          // 12.6 MB
    const size_t szBh   = (size_t)NS * DM * 2;          // 37.7 MB
    const size_t szWTb  = (size_t)NS * DM * 2;          // 37.7 MB (separate: prep writes it concurrently)
    const size_t szCand = (size_t)NB * CAP * 8;         // 67.1 MB
    const size_t szCnt  = (size_t)NB * 4;               // 32 KB
    const size_t szTV   = (size_t)NB * K * 4;           // 2 MB
    const size_t szTI   = (size_t)NB * K * 4;           // 2 MB
    const size_t szFL   = (size_t)NB * 4;               // 32 KB
    const size_t need_fast = szAh + szBh + szWTb + szCand + szCnt + szTV + szTI + szFL;  // ~160 MB

    const size_t need_fast_alias = szAh + szBh + szCand + szCnt + szTV + szTI + szFL;    // ~122 MB

    if (ws_size >= need_fast) {
        // roomy layout: WTb its own region (prep_all writes Ah/Bh/WTb in one launch)
        char* p = (char*)d_ws;
        short* Ah = (short*)p;                         p += szAh;
        short* Bh = (short*)p;                         p += szBh;
        unsigned short* WTb = (unsigned short*)p;      p += szWTb;
        unsigned long long* cand = (unsigned long long*)p;  p += szCand;
        int*   cnt = (int*)p;                          p += szCnt;
        float* tv  = (float*)p;                        p += szTV;
        int*   ti  = (int*)p;                          p += szTI;
        int*   fl  = (int*)p;

        hipMemsetAsync(zs, 0, (size_t)NB * NS * 4, stream);   // fill engine: z_sparse zeros
        hipMemsetAsync(cnt, 0, szCnt, stream);
        prep_all<<<PREP_BLKS + TR_BLKS, 256, 0, stream>>>(x, bp, We, Ah, Bh, Wd, WTb);
        encode_filter<<<dim3(NS / 128, NB / 128), 256, 0, stream>>>(Ah, Bh, be, cand, cnt);
        topk_fast<<<NB, 256, 0, stream>>>(cand, cnt, zs, x, bp, We, be, tv, ti, fl);
        topk_exact_fb<<<NB, 256, 0, stream>>>(zs, x, bp, We, be, tv, ti, fl);
        decode_bf<<<NB, 192, 0, stream>>>(tv, ti, WTb, bd, recon);
    } else if (ws_size >= need_fast_alias) {
        // round-8 layout: WTb aliases Ah|Bh, transpose runs after encode
        char* p = (char*)d_ws;
        short* Ah = (short*)p;                         p += szAh;
        short* Bh = (short*)p;                         p += szBh;
        unsigned long long* cand = (unsigned long long*)p;  p += szCand;
        int*   cnt = (int*)p;                          p += szCnt;
        float* tv  = (float*)p;                        p += szTV;
        int*   ti  = (int*)p;                          p += szTI;
        int*   fl  = (int*)p;
        unsigned short* WTb = (unsigned short*)d_ws;   // aliases Ah|Bh after encode

        hipMemsetAsync(zs, 0, (size_t)NB * NS * 4, stream);
        hipMemsetAsync(cnt, 0, szCnt, stream);
        prep_all<<<PREP_BLKS, 256, 0, stream>>>(x, bp, We, Ah, Bh, Wd, WTb);  // prep region only
        encode_filter<<<dim3(NS / 128, NB / 128), 256, 0, stream>>>(Ah, Bh, be, cand, cnt);
        // transpose via prep_all's transpose region only (blocks offset by PREP_BLKS handled below)
        prep_all<<<TR_BLKS, 256, 0, stream>>>(x, bp, We, Ah, Bh, Wd, WTb);    // would hit prep region; guard: not used
        topk_fast<<<NB, 256, 0, stream>>>(cand, cnt, zs, x, bp, We, be, tv, ti, fl);
        topk_exact_fb<<<NB, 256, 0, stream>>>(zs, x, bp, We, be, tv, ti, fl);
        decode_bf<<<NB, 192, 0, stream>>>(tv, ti, WTb, bd, recon);
    } else {
        const size_t need_small = szTV + szTI;
        float* tv = (float*)d_ws;
        int*   ti = (int*)((char*)d_ws + szTV);

        dim3 gg(NS / BN, NB / BM);
        encode_gemm<<<gg, 256, 0, stream>>>(x, We, be, bp, zs);

        if (ws_size >= need_small) {
            topk_kernel<<<NB, 256, 0, stream>>>(zs, tv, ti);
            decode_nt<<<NB, 256, 0, stream>>>(tv, ti, Wd, bd, recon);
        } else {
            topk_kernel<<<NB, 256, 0, stream>>>(zs, nullptr, nullptr);
            decode_scan<<<NB, 256, 0, stream>>>(zs, nullptr ? nullptr : Wd, bd, recon);
        }
    }
}

// Round 14
// 962.923 us; speedup vs baseline: 1.6707x; 1.0023x over previous
//
#include <hip/hip_runtime.h>
#include <hip/hip_bf16.h>

// Problem constants (fixed by the reference)
constexpr int DM = 768;     // d_model (GEMM K dim)
constexpr int NS = 24576;   // d_sae
constexpr int NB = 8192;    // batch
constexpr int K  = 64;      // top-k

constexpr int CAP   = 1024;  // per-row candidate capacity (expected ~462, +26 sigma)
constexpr int BANDC = 256;   // refinement band capacity
constexpr int RCAP  = 16;    // per-row per-block LDS bucket (expected 2.4; lossless overflow)
#define T0F   1.2f           // candidate pre-threshold (guarded; fallback if violated)
#define DELTA 0.015f         // selection uncertainty band >= 2*bf16-GEMM error (~0.007)

typedef __attribute__((ext_vector_type(8))) short short8v;
typedef __attribute__((ext_vector_type(4))) short short4v;
typedef __attribute__((ext_vector_type(4))) float f32x4;

__device__ __forceinline__ unsigned short f2bf(float f) {
    unsigned u = __float_as_uint(f);
    u += 0x7FFFu + ((u >> 16) & 1u);          // RNE, finite inputs only
    return (unsigned short)(u >> 16);
}
__device__ __forceinline__ float bf2f(unsigned short h) {
    return __uint_as_float(((unsigned)h) << 16);
}
__device__ __forceinline__ unsigned fkey(float f) {
    unsigned u = __float_as_uint(f);
    return (u & 0x80000000u) ? ~u : (u | 0x80000000u);   // monotonic ascending, all floats
}
__device__ __forceinline__ float key2f(unsigned k) {
    unsigned u = (k & 0x80000000u) ? (k & 0x7FFFFFFFu) : ~k;
    return __uint_as_float(u);
}

// ============ fused prep: bf16 A+B convert, W_dec transpose, cnt zeroing ============
constexpr int PREP_BLKS = (NB * 192 + NS * 192) / 256;   // 24576
constexpr int TR_BLKS   = (NS / 32) * (DM / 32);         // 18432
constexpr int CNT_BLKS  = NB / 256;                      // 32

__global__ __launch_bounds__(256) void prep_all(
    const float* __restrict__ x, const float* __restrict__ bp,
    const float* __restrict__ We, short* __restrict__ Ah, short* __restrict__ Bh,
    const float* __restrict__ Wd, unsigned short* __restrict__ WTb,
    int* __restrict__ cnt)
{
    __shared__ float tile[32][33];
    const int blk = blockIdx.x;
    if (blk < PREP_BLKS) {
        const int i = blk * 256 + threadIdx.x;
        constexpr int NA = NB * 192;                 // A-region float4 count
        if (i < NA) {
            const int row = i / 192;
            const int c = (i % 192) * 4;
            const float4 xv = *(const float4*)&x[(size_t)row * DM + c];
            const float4 pv = *(const float4*)&bp[c];
            float a[4] = {xv.x - pv.x, xv.y - pv.y, xv.z - pv.z, xv.w - pv.w};
            short4v h;
            #pragma unroll
            for (int j = 0; j < 4; ++j) h[j] = (short)f2bf(a[j]);
            *(short4v*)&Ah[(size_t)row * DM + c] = h;
        } else {
            const int j2 = i - NA;
            const int row = j2 / 192;
            const int c = (j2 % 192) * 4;
            const float4 wv = *(const float4*)&We[(size_t)row * DM + c];
            float a[4] = {wv.x, wv.y, wv.z, wv.w};
            short4v h;
            #pragma unroll
            for (int j = 0; j < 4; ++j) h[j] = (short)f2bf(a[j]);
            *(short4v*)&Bh[(size_t)row * DM + c] = h;
        }
    } else if (blk < PREP_BLKS + TR_BLKS) {
        const int i2 = blk - PREP_BLKS;
        const int bx = (i2 % (NS / 32)) * 32;   // s
        const int by = (i2 / (NS / 32)) * 32;   // d
        const int tx = threadIdx.x & 31;
        const int ty = threadIdx.x >> 5;        // 0..7
        #pragma unroll
        for (int r = 0; r < 32; r += 8)
            tile[ty + r][tx] = Wd[(size_t)(by + ty + r) * NS + bx + tx];
        __syncthreads();
        #pragma unroll
        for (int r = 0; r < 32; r += 8)
            WTb[(size_t)(bx + ty + r) * DM + by + tx] = f2bf(tile[tx][ty + r]);
    } else {
        const int i3 = (blk - PREP_BLKS - TR_BLKS) * 256 + threadIdx.x;
        if (i3 < NB) cnt[i3] = 0;
    }
}

// ============ bf16 MFMA encode GEMM + fused z_sparse zero-fill
//              + per-row-bucket filter epilogue ============
// Round-8 proven K-loop (single buffer set, 16 KB; lbuf aliases it after the
// loop). NEW: each block zeroes its 64 KB chunk of z_sparse after the K-loop —
// encode uses only ~20% HBM BW, so these coalesced stores ride the idle write
// port and replace the 122 us serialized fill-engine memset.
__global__ __launch_bounds__(256) void encode_filter(
    const short* __restrict__ Ah, const short* __restrict__ Bh,
    const float* __restrict__ be,
    unsigned long long* __restrict__ cand, int* __restrict__ cnt,
    float* __restrict__ zs)
{
    __shared__ __align__(16) char smem[16384];
    short* Ash = (short*)smem;
    short* Bsh = (short*)(smem + 8192);
    unsigned long long* lbuf = (unsigned long long*)smem;   // aliases staging after K-loop
    __shared__ int lcnt[128];

    const int t = threadIdx.x;
    const int l = t & 63;
    const int w = t >> 6;           // wave 0..3 -> (wm,wn) in 2x2
    const int wm = w >> 1, wn = w & 1;
    const int bm = blockIdx.y * 128;
    const int bn = blockIdx.x * 128;

    const int srow = l >> 2;                              // staging: row within 16-row chunk
    const int gsrc = (((l & 3) ^ ((l >> 2) & 3)) * 8);    // staging k-granule swizzle (r8-verified)
    const int lr = l & 15;
    const int gs8 = (((l >> 4) ^ (l & 3)) * 8);           // matching read granule

    f32x4 acc[4][4];
    #pragma unroll
    for (int m = 0; m < 4; ++m)
        #pragma unroll
        for (int n = 0; n < 4; ++n)
            acc[m][n] = f32x4{0.f, 0.f, 0.f, 0.f};

    for (int ks = 0; ks < DM; ks += 32) {
        __syncthreads();
        #pragma unroll
        for (int h = 0; h < 2; ++h) {
            const int c = w * 2 + h;            // chunk 0..7 (wave-uniform)
            const int row = c * 16 + srow;      // tile row 0..127
            __builtin_amdgcn_global_load_lds(
                (const __attribute__((address_space(1))) void*)(Ah + (size_t)(bm + row) * DM + ks + gsrc),
                (__attribute__((address_space(3))) void*)(Ash + c * 512), 16, 0, 0);
            __builtin_amdgcn_global_load_lds(
                (const __attribute__((address_space(1))) void*)(Bh + (size_t)(bn + row) * DM + ks + gsrc),
                (__attribute__((address_space(3))) void*)(Bsh + c * 512), 16, 0, 0);
        }
        __syncthreads();

        short8v a[4], b[4];
        #pragma unroll
        for (int m = 0; m < 4; ++m)
            a[m] = *(const short8v*)&Ash[(wm * 64 + m * 16 + lr) * 32 + gs8];
        #pragma unroll
        for (int n = 0; n < 4; ++n)
            b[n] = *(const short8v*)&Bsh[(wn * 64 + n * 16 + lr) * 32 + gs8];
        #pragma unroll
        for (int m = 0; m < 4; ++m)
            #pragma unroll
            for (int n = 0; n < 4; ++n)
                acc[m][n] = __builtin_amdgcn_mfma_f32_16x16x32_bf16(a[m], b[n], acc[m][n], 0, 0, 0);
    }

    // fused z_sparse zero-fill: this block's 64 KB chunk (coalesced float4)
    {
        const int bid = blockIdx.y * gridDim.x + blockIdx.x;     // 0..12287
        f32x4* zp = (f32x4*)(zs + (size_t)bid * 16384);          // 4096 f32x4
        const f32x4 z4 = {0.f, 0.f, 0.f, 0.f};
        #pragma unroll
        for (int i = 0; i < 16; ++i)
            zp[i * 256 + t] = z4;
    }

    // staging tiles now dead: hand the LDS to the buckets
    __syncthreads();                 // all waves' frag reads retired
    if (t < 128) lcnt[t] = 0;
    __syncthreads();                 // lcnt visible; lbuf alias safe

    // ---- stage 1: predicated per-row LDS bucket push ----
    // C/D layout: col = lane&15, row = (lane>>4)*4 + r
    #pragma unroll
    for (int n = 0; n < 4; ++n) {
        const int colg = bn + wn * 64 + n * 16 + lr;
        const float bev = be[colg];
        #pragma unroll
        for (int m = 0; m < 4; ++m) {
            const int rl0 = wm * 64 + m * 16 + (l >> 4) * 4;
            #pragma unroll
            for (int r = 0; r < 4; ++r) {
                const float v = acc[m][n][r] + bev;
                if (v >= T0F) {
                    const int rl = rl0 + r;
                    const unsigned long long e =
                        ((unsigned long long)__float_as_uint(v) << 32) | (unsigned)colg;
                    const int p = atomicAdd(&lcnt[rl], 1);
                    if (p < RCAP) {
                        lbuf[rl * RCAP + p] = e;
                    } else {
                        // lossless slow path on bucket overflow (rare)
                        const int q = atomicAdd(&cnt[bm + rl], 1);
                        if (q < CAP) cand[(size_t)(bm + rl) * CAP + q] = e;
                    }
                }
            }
        }
    }
    __syncthreads();

    // ---- stage 2: one global atomic per row, parallel copy ----
    if (t < 128) {
        int c = lcnt[t]; if (c > RCAP) c = RCAP;
        if (c > 0) {
            const int rowg = bm + t;
            const int base = atomicAdd(&cnt[rowg], c);
            for (int i = 0; i < c; ++i) {
                const int p = base + i;
                if (p < CAP) cand[(size_t)rowg * CAP + p] = lbuf[t * RCAP + i];
            }
        }
    }
}

// ============ fast top-k on candidate lists (LDS radix + exact band) ============
// z_sparse pre-zeroed by encode_filter's fused fill: scatter-only here.
__global__ __launch_bounds__(256) void topk_fast(
    const unsigned long long* __restrict__ cand, const int* __restrict__ cnt,
    float* __restrict__ z,
    const float* __restrict__ x, const float* __restrict__ bp,
    const float* __restrict__ We, const float* __restrict__ be,
    float* __restrict__ tv, int* __restrict__ ti, int* __restrict__ rowflag)
{
    const int row = blockIdx.x;
    const int t = threadIdx.x;
    const int l = t & 63;
    const int w = t >> 6;
    float* zr = z + (size_t)row * NS;

    const int cc = cnt[row];
    if (cc < K || cc > CAP) { if (t == 0) rowflag[row] = 1; return; }

    __shared__ unsigned ckey[CAP];
    __shared__ int      cidx[CAP];
    __shared__ unsigned hist[256];
    __shared__ int   bandi[BANDC];
    __shared__ float bexa[BANDC];
    __shared__ int   cini[K];
    __shared__ float cinf[K];
    __shared__ int   seli[K];
    __shared__ float selv[K];
    __shared__ unsigned s_prefix, s_pmask;
    __shared__ int s_need, s_cin, s_bc, s_ns;

    const unsigned long long* cr = cand + (size_t)row * CAP;
    for (int i = t; i < cc; i += 256) {
        const unsigned long long pk = cr[i];
        ckey[i] = (unsigned)(pk >> 32);          // raw f32 bits; all >= T0F > 0 -> monotonic
        cidx[i] = (int)(unsigned)(pk & 0xFFFFFFFFull);
    }
    if (t == 0) { s_prefix = 0u; s_pmask = 0u; s_need = K; s_cin = 0; s_bc = 0; s_ns = 0; }
    __syncthreads();

    // exact radix select of rank-K key (4 x 8-bit passes, LDS only)
    for (int shift = 24; shift >= 0; shift -= 8) {
        hist[t] = 0u;
        __syncthreads();
        const unsigned prefix = s_prefix, pmask = s_pmask;
        for (int c = t; c < cc; c += 256) {
            const unsigned u = ckey[c];
            if ((u & pmask) == prefix) atomicAdd(&hist[(u >> shift) & 255u], 1u);
        }
        __syncthreads();
        if (t == 0) {
            int need = s_need; unsigned cum = 0; int sel = 0;
            for (int b = 255; b >= 0; --b) {
                if (cum + hist[b] >= (unsigned)need) { sel = b; break; }
                cum += hist[b];
            }
            s_need = need - (int)cum;
            s_prefix = prefix | ((unsigned)sel << shift);
            s_pmask = pmask | (0xFFu << shift);
        }
        __syncthreads();
    }

    const float Tf = __uint_as_float(s_prefix);
    if (Tf - DELTA < T0F) { if (t == 0) rowflag[row] = 1; return; }   // band dips under pre-threshold
    const unsigned khi = __float_as_uint(Tf + DELTA);
    const unsigned klo = __float_as_uint(Tf - DELTA);

    for (int c = t; c < cc; c += 256) {
        const unsigned u = ckey[c];
        if (u > khi) {                       // certainly in true top-K
            const int p = atomicAdd(&s_cin, 1);
            if (p < K) { cini[p] = cidx[c]; cinf[p] = __uint_as_float(u); }
        } else if (u >= klo) {               // boundary band: exact comparison needed
            const int p = atomicAdd(&s_bc, 1);
            if (p < BANDC) bandi[p] = cidx[c];
        }
    }
    __syncthreads();
    const int cin  = s_cin;
    const int bc   = s_bc;
    const int nsel = K - cin;
    if (cin >= K || bc > BANDC || bc < nsel) { if (t == 0) rowflag[row] = 1; return; }

    // exact fp32 dots for band members (one wave per member, round-robin)
    const float* xr = x + (size_t)row * DM;
    for (int c = w; c < bc; c += 4) {
        const int s = bandi[c];
        const float* wr = We + (size_t)s * DM;
        float acc = 0.f;
        for (int k = l; k < DM; k += 64)
            acc = fmaf(xr[k] - bp[k], wr[k], acc);
        #pragma unroll
        for (int off = 32; off > 0; off >>= 1) acc += __shfl_xor(acc, off);
        if (l == 0) bexa[c] = acc + be[s];
    }
    __syncthreads();

    // band ranking by (exact desc, index asc); take top nsel
    if (t < bc) {
        const float myv = bexa[t];
        const int myi = bandi[t];
        int rk = 0;
        for (int j = 0; j < bc; ++j) {
            const float vj = bexa[j];
            rk += (vj > myv) || (vj == myv && bandi[j] < myi);
        }
        if (rk < nsel) {
            const int p = atomicAdd(&s_ns, 1);
            if (p < K) { seli[p] = myi; selv[p] = myv; }
        }
    }
    if (t < cin) {
        const int p = atomicAdd(&s_ns, 1);
        if (p < K) { seli[p] = cini[t]; selv[p] = cinf[t]; }
    }
    __syncthreads();
    if (s_ns != K) { if (t == 0) rowflag[row] = 1; return; }
    if (t == 0) rowflag[row] = 0;

    // scatter selected (row pre-zeroed); slots rank-sorted by index -> deterministic
    if (t < K) {
        const int   myi = seli[t];
        const float myv = selv[t];
        int r = 0;
        #pragma unroll 8
        for (int j = 0; j < K; ++j) r += (seli[j] < myi);
        zr[myi] = myv;
        tv[(size_t)row * K + r] = myv;
        ti[(size_t)row * K + r] = myi;
    }
}

// ============ exact self-contained fallback (flagged rows only) ============
constexpr int XCAP = 6144;
#define XT0 0.8f

__global__ __launch_bounds__(256) void topk_exact_fb(
    float* __restrict__ z,
    const float* __restrict__ x, const float* __restrict__ bp,
    const float* __restrict__ We, const float* __restrict__ be,
    float* __restrict__ tv, int* __restrict__ ti, const int* __restrict__ rowflag)
{
    const int row = blockIdx.x;
    if (rowflag[row] == 0) return;
    const int t = threadIdx.x;
    float* zr = z + (size_t)row * NS;
    const float* xr = x + (size_t)row * DM;

    __shared__ unsigned xkey[XCAP];
    __shared__ int      xidx[XCAP];
    __shared__ unsigned hist[256];
    __shared__ int   eq[128];
    __shared__ float selv[K];
    __shared__ int   seli[K];
    __shared__ unsigned s_prefix, s_pmask;
    __shared__ int s_cnt, s_need, s_eqc, s_ns;

    if (t == 0) { s_cnt = 0; s_eqc = 0; s_ns = 0; s_prefix = 0u; s_pmask = 0u; s_need = K; }
    __syncthreads();

    // stage 1: exact recompute of row, collect values >= XT0
    for (int j = t; j < NS; j += 256) {
        const float* wr = We + (size_t)j * DM;
        float acc = 0.f;
        for (int k = 0; k < DM; ++k) acc = fmaf(xr[k] - bp[k], wr[k], acc);
        const float v = acc + be[j];
        if (v >= XT0) {
            const int p = atomicAdd(&s_cnt, 1);
            if (p < XCAP) { xkey[p] = fkey(v); xidx[p] = j; }
        }
    }
    __syncthreads();
    const int cc = s_cnt;

    if (cc >= K && cc <= XCAP) {
        // --- path A: radix on LDS list of exact values ---
        for (int shift = 24; shift >= 0; shift -= 8) {
            hist[t] = 0u;
            __syncthreads();
            const unsigned prefix = s_prefix, pmask = s_pmask;
            for (int c = t; c < cc; c += 256) {
                const unsigned u = xkey[c];
                if ((u & pmask) == prefix) atomicAdd(&hist[(u >> shift) & 255u], 1u);
            }
            __syncthreads();
            if (t == 0) {
                int need = s_need; unsigned cum = 0; int sel = 0;
                for (int b = 255; b >= 0; --b) {
                    if (cum + hist[b] >= (unsigned)need) { sel = b; break; }
                    cum += hist[b];
                }
                s_need = need - (int)cum;
                s_prefix = prefix | ((unsigned)sel << shift);
                s_pmask = pmask | (0xFFu << shift);
            }
            __syncthreads();
        }
        const unsigned T = s_prefix;
        const int need = s_need;

        for (int c = t; c < cc; c += 256)
            if (xkey[c] == T) { const int p = atomicAdd(&s_eqc, 1); if (p < 128) eq[p] = xidx[c]; }
        __syncthreads();
        if (t == 0) {   // keep `need` smallest tie indices
            int nn = s_eqc < 128 ? s_eqc : 128;
            int lim = need < nn ? need : nn;
            for (int a = 0; a < lim; ++a) {
                int mi = a;
                for (int b = a + 1; b < nn; ++b) if (eq[b] < eq[mi]) mi = b;
                int tmp = eq[a]; eq[a] = eq[mi]; eq[mi] = tmp;
            }
        }
        __syncthreads();

        for (int c = t; c < cc; c += 256) {
            const unsigned u = xkey[c];
            bool take = (u > T);
            if (u == T)
                for (int a = 0; a < need; ++a) if (eq[a] == xidx[c]) { take = true; break; }
            if (take) {
                const int p = atomicAdd(&s_ns, 1);
                if (p < K) { selv[p] = key2f(u); seli[p] = xidx[c]; }
            }
        }
        __syncthreads();
    } else {
        // --- path B: guaranteed full radix with per-pass recompute ---
        for (int shift = 24; shift >= 0; shift -= 8) {
            hist[t] = 0u;
            __syncthreads();
            const unsigned prefix = s_prefix, pmask = s_pmask;
            for (int j = t; j < NS; j += 256) {
                const float* wr = We + (size_t)j * DM;
                float acc = 0.f;
                for (int k = 0; k < DM; ++k) acc = fmaf(xr[k] - bp[k], wr[k], acc);
                const unsigned u = fkey(acc + be[j]);
                if ((u & pmask) == prefix) atomicAdd(&hist[(u >> shift) & 255u], 1u);
            }
            __syncthreads();
            if (t == 0) {
                int need = s_need; unsigned cum = 0; int sel = 0;
                for (int b = 255; b >= 0; --b) {
                    if (cum + hist[b] >= (unsigned)need) { sel = b; break; }
                    cum += hist[b];
                }
                s_need = need - (int)cum;
                s_prefix = prefix | ((unsigned)sel << shift);
                s_pmask = pmask | (0xFFu << shift);
            }
            __syncthreads();
        }
        const unsigned T = s_prefix;
        const int need = s_need;

        for (int j = t; j < NS; j += 256) {
            const float* wr = We + (size_t)j * DM;
            float acc = 0.f;
            for (int k = 0; k < DM; ++k) acc = fmaf(xr[k] - bp[k], wr[k], acc);
            if (fkey(acc + be[j]) == T) { const int p = atomicAdd(&s_eqc, 1); if (p < 128) eq[p] = j; }
        }
        __syncthreads();
        if (t == 0) {
            int nn = s_eqc < 128 ? s_eqc : 128;
            int lim = need < nn ? need : nn;
            for (int a = 0; a < lim; ++a) {
                int mi = a;
                for (int b = a + 1; b < nn; ++b) if (eq[b] < eq[mi]) mi = b;
                int tmp = eq[a]; eq[a] = eq[mi]; eq[mi] = tmp;
            }
        }
        __syncthreads();

        for (int j = t; j < NS; j += 256) {
            const float* wr = We + (size_t)j * DM;
            float acc = 0.f;
            for (int k = 0; k < DM; ++k) acc = fmaf(xr[k] - bp[k], wr[k], acc);
            const float v = acc + be[j];
            const unsigned u = fkey(v);
            bool take = (u > T);
            if (u == T)
                for (int a = 0; a < need; ++a) if (eq[a] == j) { take = true; break; }
            if (take) {
                const int p = atomicAdd(&s_ns, 1);
                if (p < K) { selv[p] = v; seli[p] = j; }
            }
        }
        __syncthreads();
    }

    // scatter + tv/ti (row pre-zeroed by encode's fused fill)
    const int ns = s_ns < K ? s_ns : K;
    if (t < ns) {
        const int   myi = seli[t];
        const float myv = selv[t];
        int r = 0;
        for (int j = 0; j < ns; ++j) r += (seli[j] < myi);
        zr[myi] = myv;
        tv[(size_t)row * K + r] = myv;
        ti[(size_t)row * K + r] = myi;
    }
}

// ============ sparse decode (bf16 transposed weights, vectorized 8B/lane) ============
__global__ __launch_bounds__(192) void decode_bf(
    const float* __restrict__ tv, const int* __restrict__ ti,
    const unsigned short* __restrict__ WTb, const float* __restrict__ bd,
    float* __restrict__ recon)
{
    const int row = blockIdx.x;
    const int t = threadIdx.x;        // 192 threads, each owns 4 contiguous d
    __shared__ float sv[K];
    __shared__ int   si[K];
    if (t < K) { sv[t] = tv[(size_t)row * K + t]; si[t] = ti[(size_t)row * K + t]; }
    __syncthreads();
    const int d0 = t * 4;
    float4 a = *(const float4*)&bd[d0];
    #pragma unroll 4
    for (int k = 0; k < K; ++k) {
        const ushort4 wv = *(const ushort4*)(WTb + (size_t)si[k] * DM + d0);
        const float v = sv[k];
        a.x = fmaf(v, bf2f(wv.x), a.x);
        a.y = fmaf(v, bf2f(wv.y), a.y);
        a.z = fmaf(v, bf2f(wv.z), a.z);
        a.w = fmaf(v, bf2f(wv.w), a.w);
    }
    *(float4*)&recon[(size_t)row * DM + d0] = a;
}

// ===================== small-ws legacy path (round-1, validated) =====================
#define BM 128
#define BN 128
#define BK 16

__global__ __launch_bounds__(256) void encode_gemm(
    const float* __restrict__ x, const float* __restrict__ We,
    const float* __restrict__ be, const float* __restrict__ bp,
    float* __restrict__ z)
{
    __shared__ __align__(16) float As[BK][BM + 4];
    __shared__ __align__(16) float Bs[BK][BN + 4];

    const int t  = threadIdx.x;
    const int bm = blockIdx.y * BM;
    const int bn = blockIdx.x * BN;
    const int tm = (t / 16) * 8;
    const int tn = (t % 16) * 8;

    float acc[8][8] = {};

    for (int k0 = 0; k0 < DM; k0 += BK) {
        #pragma unroll
        for (int h = 0; h < 2; ++h) {
            const int q  = t + h * 256;
            const int m  = q >> 2;
            const int kq = (q & 3) * 4;
            const float4 av = *(const float4*)&x[(size_t)(bm + m) * DM + k0 + kq];
            const float4 pv = *(const float4*)&bp[k0 + kq];
            As[kq + 0][m] = av.x - pv.x;
            As[kq + 1][m] = av.y - pv.y;
            As[kq + 2][m] = av.z - pv.z;
            As[kq + 3][m] = av.w - pv.w;
            const float4 bv = *(const float4*)&We[(size_t)(bn + m) * DM + k0 + kq];
            Bs[kq + 0][m] = bv.x;
            Bs[kq + 1][m] = bv.y;
            Bs[kq + 2][m] = bv.z;
            Bs[kq + 3][m] = bv.w;
        }
        __syncthreads();

        #pragma unroll
        for (int kk = 0; kk < BK; ++kk) {
            float a[8], b[8];
            *(float4*)&a[0] = *(const float4*)&As[kk][tm];
            *(float4*)&a[4] = *(const float4*)&As[kk][tm + 4];
            *(float4*)&b[0] = *(const float4*)&Bs[kk][tn];
            *(float4*)&b[4] = *(const float4*)&Bs[kk][tn + 4];
            #pragma unroll
            for (int i = 0; i < 8; ++i)
                #pragma unroll
                for (int j = 0; j < 8; ++j)
                    acc[i][j] = fmaf(a[i], b[j], acc[i][j]);
        }
        __syncthreads();
    }

    float4 be0 = *(const float4*)&be[bn + tn];
    float4 be1 = *(const float4*)&be[bn + tn + 4];
    #pragma unroll
    for (int i = 0; i < 8; ++i) {
        const size_t rowoff = (size_t)(bm + tm + i) * NS + bn + tn;
        float4 c0, c1;
        c0.x = acc[i][0] + be0.x; c0.y = acc[i][1] + be0.y;
        c0.z = acc[i][2] + be0.z; c0.w = acc[i][3] + be0.w;
        c1.x = acc[i][4] + be1.x; c1.y = acc[i][5] + be1.y;
        c1.z = acc[i][6] + be1.z; c1.w = acc[i][7] + be1.w;
        *(float4*)&z[rowoff]     = c0;
        *(float4*)&z[rowoff + 4] = c1;
    }
}

__global__ __launch_bounds__(256) void topk_kernel(
    float* __restrict__ z, float* __restrict__ tv, int* __restrict__ ti)
{
    const int row = blockIdx.x;
    float* zr = z + (size_t)row * NS;
    const int t = threadIdx.x;

    __shared__ unsigned hist[256];
    __shared__ unsigned s_prefix, s_pmask;
    __shared__ int s_need;
    __shared__ int eqidx[128];
    __shared__ int eqcnt, outcnt;
    __shared__ float osv[K];
    __shared__ int   osi[K];

    if (t == 0) { s_prefix = 0u; s_pmask = 0u; s_need = K; eqcnt = 0; outcnt = 0; }
    __syncthreads();

    for (int shift = 24; shift >= 0; shift -= 8) {
        hist[t] = 0u;
        __syncthreads();
        const unsigned prefix = s_prefix, pmask = s_pmask;
        for (int i = t; i < NS; i += 256) {
            unsigned u = fkey(zr[i]);
            if ((u & pmask) == prefix) atomicAdd(&hist[(u >> shift) & 255u], 1u);
        }
        __syncthreads();
        if (t == 0) {
            int need = s_need;
            unsigned cum = 0; int sel = 0;
            for (int b = 255; b >= 0; --b) {
                if (cum + hist[b] >= (unsigned)need) { sel = b; break; }
                cum += hist[b];
            }
            s_need   = need - (int)cum;
            s_prefix = prefix | ((unsigned)sel << shift);
            s_pmask  = pmask | (0xFFu << shift);
        }
        __syncthreads();
    }

    const unsigned T = s_prefix;
    const int need = s_need;

    for (int i = t; i < NS; i += 256) {
        if (fkey(zr[i]) == T) {
            int p = atomicAdd(&eqcnt, 1);
            if (p < 128) eqidx[p] = i;
        }
    }
    __syncthreads();
    if (t == 0) {
        int nn = eqcnt < 128 ? eqcnt : 128;
        int lim = need < nn ? need : nn;
        for (int a = 0; a < lim; ++a) {
            int mi = a;
            for (int b = a + 1; b < nn; ++b) if (eqidx[b] < eqidx[mi]) mi = b;
            int tmp = eqidx[a]; eqidx[a] = eqidx[mi]; eqidx[mi] = tmp;
        }
    }
    __syncthreads();

    for (int i = t; i < NS; i += 256) {
        const float v = zr[i];
        const unsigned u = fkey(v);
        bool take = (u > T);
        if (u == T) {
            for (int a = 0; a < need; ++a) if (eqidx[a] == i) { take = true; break; }
        }
        if (take) {
            int p = atomicAdd(&outcnt, 1);
            if (p < K) { osv[p] = v; osi[p] = i; }
        } else {
            zr[i] = 0.0f;
        }
    }
    __syncthreads();

    if (tv != nullptr && t < K) {
        const int   myi = osi[t];
        const float myv = osv[t];
        int r = 0;
        #pragma unroll 8
        for (int j = 0; j < K; ++j) r += (osi[j] < myi);
        tv[(size_t)row * K + r] = myv;
        ti[(size_t)row * K + r] = myi;
    }
}

__global__ __launch_bounds__(256) void decode_nt(
    const float* __restrict__ tv, const int* __restrict__ ti,
    const float* __restrict__ Wd, const float* __restrict__ bd,
    float* __restrict__ recon)
{
    const int row = blockIdx.x;
    const int t = threadIdx.x;
    __shared__ float sv[K];
    __shared__ int   si[K];
    if (t < K) { sv[t] = tv[(size_t)row * K + t]; si[t] = ti[(size_t)row * K + t]; }
    __syncthreads();
    float a0 = bd[t], a1 = bd[t + 256], a2 = bd[t + 512];
    for (int k = 0; k < K; ++k) {
        const float v = sv[k];
        const int s = si[k];
        a0 = fmaf(v, Wd[(size_t)t * NS + s],         a0);
        a1 = fmaf(v, Wd[(size_t)(t + 256) * NS + s], a1);
        a2 = fmaf(v, Wd[(size_t)(t + 512) * NS + s], a2);
    }
    float* rr = recon + (size_t)row * DM;
    rr[t] = a0; rr[t + 256] = a1; rr[t + 512] = a2;
}

__global__ __launch_bounds__(256) void decode_scan(
    const float* __restrict__ z, const float* __restrict__ Wd,
    const float* __restrict__ bd, float* __restrict__ recon)
{
    constexpr int CAP2 = 96;
    const int row = blockIdx.x;
    const int t = threadIdx.x;
    __shared__ float sv[CAP2], sv2[CAP2];
    __shared__ int   si[CAP2], si2[CAP2];
    __shared__ int cnt;
    if (t == 0) cnt = 0;
    __syncthreads();
    const float* zr = z + (size_t)row * NS;
    for (int i = t; i < NS; i += 256) {
        float v = zr[i];
        if (v != 0.0f) { int p = atomicAdd(&cnt, 1); if (p < CAP2) { sv[p] = v; si[p] = i; } }
    }
    __syncthreads();
    const int n = cnt < CAP2 ? cnt : CAP2;
    if (t < n) {
        int myi = si[t]; int r = 0;
        for (int j = 0; j < n; ++j) r += (si[j] < myi);
        sv2[r] = sv[t]; si2[r] = myi;
    }
    __syncthreads();
    float a0 = bd[t], a1 = bd[t + 256], a2 = bd[t + 512];
    for (int k = 0; k < n; ++k) {
        const float v = sv2[k];
        const int s = si2[k];
        a0 = fmaf(v, Wd[(size_t)t * NS + s],         a0);
        a1 = fmaf(v, Wd[(size_t)(t + 256) * NS + s], a1);
        a2 = fmaf(v, Wd[(size_t)(t + 512) * NS + s], a2);
    }
    float* rr = recon + (size_t)row * DM;
    rr[t] = a0; rr[t + 256] = a1; rr[t + 512] = a2;
}

// ===================== launch =====================
extern "C" void kernel_launch(void* const* d_in, const int* in_sizes, int n_in,
                              void* d_out, int out_size, void* d_ws, size_t ws_size,
                              hipStream_t stream) {
    const float* x  = (const float*)d_in[0];
    const float* We = (const float*)d_in[1];
    const float* be = (const float*)d_in[2];
    const float* Wd = (const float*)d_in[3];
    const float* bd = (const float*)d_in[4];
    const float* bp = (const float*)d_in[5];

    float* recon = (float*)d_out;                       // [8192][768]
    float* zs    = recon + (size_t)NB * DM;             // [8192][24576] (z_sparse)

    const size_t szAh   = (size_t)NB * DM * 2;          // 12.6 MB
    const size_t szBh   = (size_t)NS * DM * 2;          // 37.7 MB
    const size_t szWTb  = (size_t)NS * DM * 2;          // 37.7 MB
    const size_t szCand = (size_t)NB * CAP * 8;         // 67.1 MB
    const size_t szCnt  = (size_t)NB * 4;               // 32 KB
    const size_t szTV   = (size_t)NB * K * 4;           // 2 MB
    const size_t szTI   = (size_t)NB * K * 4;           // 2 MB
    const size_t szFL   = (size_t)NB * 4;               // 32 KB
    const size_t need_fast = szAh + szBh + szWTb + szCand + szCnt + szTV + szTI + szFL;  // ~160 MB (validated available in r13)

    if (ws_size >= need_fast) {
        char* p = (char*)d_ws;
        short* Ah = (short*)p;                         p += szAh;
        short* Bh = (short*)p;                         p += szBh;
        unsigned short* WTb = (unsigned short*)p;      p += szWTb;
        unsigned long long* cand = (unsigned long long*)p;  p += szCand;
        int*   cnt = (int*)p;                          p += szCnt;
        float* tv  = (float*)p;                        p += szTV;
        int*   ti  = (int*)p;                          p += szTI;
        int*   fl  = (int*)p;

        prep_all<<<PREP_BLKS + TR_BLKS + CNT_BLKS, 256, 0, stream>>>(x, bp, We, Ah, Bh, Wd, WTb, cnt);
        encode_filter<<<dim3(NS / 128, NB / 128), 256, 0, stream>>>(Ah, Bh, be, cand, cnt, zs);
        topk_fast<<<NB, 256, 0, stream>>>(cand, cnt, zs, x, bp, We, be, tv, ti, fl);
        topk_exact_fb<<<NB, 256, 0, stream>>>(zs, x, bp, We, be, tv, ti, fl);
        decode_bf<<<NB, 192, 0, stream>>>(tv, ti, WTb, bd, recon);
    } else {
        const size_t need_small = szTV + szTI;
        float* tv = (float*)d_ws;
        int*   ti = (int*)((char*)d_ws + szTV);

        dim3 gg(NS / BN, NB / BM);
        encode_gemm<<<gg, 256, 0, stream>>>(x, We, be, bp, zs);

        if (ws_size >= need_small) {
            topk_kernel<<<NB, 256, 0, stream>>>(zs, tv, ti);
            decode_nt<<<NB, 256, 0, stream>>>(tv, ti, Wd, bd, recon);
        } else {
            topk_kernel<<<NB, 256, 0, stream>>>(zs, nullptr, nullptr);
            decode_scan<<<NB, 256, 0, stream>>>(zs, Wd, bd, recon);
        }
    }
}

// Round 15
// 936.039 us; speedup vs baseline: 1.7187x; 1.0287x over previous
//
#include <hip/hip_runtime.h>
#include <hip/hip_bf16.h>

// Problem constants (fixed by the reference)
constexpr int DM = 768;     // d_model (GEMM K dim)
constexpr int NS = 24576;   // d_sae
constexpr int NB = 8192;    // batch
constexpr int K  = 64;      // top-k

constexpr int CAP   = 1024;  // per-row candidate capacity (expected ~462, +26 sigma)
constexpr int BANDC = 256;   // refinement band capacity
constexpr int RCAP  = 16;    // per-row per-block LDS bucket (expected 2.4; lossless overflow)
#define T0F   1.2f           // candidate pre-threshold (guarded; fallback if violated)
#define DELTA 0.015f         // selection uncertainty band >= 2*bf16-GEMM error (~0.007)

typedef __attribute__((ext_vector_type(8))) short short8v;
typedef __attribute__((ext_vector_type(4))) short short4v;
typedef __attribute__((ext_vector_type(4))) float f32x4;

__device__ __forceinline__ unsigned short f2bf(float f) {
    unsigned u = __float_as_uint(f);
    u += 0x7FFFu + ((u >> 16) & 1u);          // RNE, finite inputs only
    return (unsigned short)(u >> 16);
}
__device__ __forceinline__ float bf2f(unsigned short h) {
    return __uint_as_float(((unsigned)h) << 16);
}
__device__ __forceinline__ unsigned fkey(float f) {
    unsigned u = __float_as_uint(f);
    return (u & 0x80000000u) ? ~u : (u | 0x80000000u);   // monotonic ascending, all floats
}
__device__ __forceinline__ float key2f(unsigned k) {
    unsigned u = (k & 0x80000000u) ? (k & 0x7FFFFFFFu) : ~k;
    return __uint_as_float(u);
}

// ============ fused prep: bf16 A+B convert, W_dec transpose, cnt zeroing ============
constexpr int PREP_BLKS = (NB * 192 + NS * 192) / 256;   // 24576
constexpr int TR_BLKS   = (NS / 32) * (DM / 32);         // 18432
constexpr int CNT_BLKS  = NB / 256;                      // 32

__global__ __launch_bounds__(256) void prep_all(
    const float* __restrict__ x, const float* __restrict__ bp,
    const float* __restrict__ We, short* __restrict__ Ah, short* __restrict__ Bh,
    const float* __restrict__ Wd, unsigned short* __restrict__ WTb,
    int* __restrict__ cnt)
{
    __shared__ float tile[32][33];
    const int blk = blockIdx.x;
    if (blk < PREP_BLKS) {
        const int i = blk * 256 + threadIdx.x;
        constexpr int NA = NB * 192;                 // A-region float4 count
        if (i < NA) {
            const int row = i / 192;
            const int c = (i % 192) * 4;
            const float4 xv = *(const float4*)&x[(size_t)row * DM + c];
            const float4 pv = *(const float4*)&bp[c];
            float a[4] = {xv.x - pv.x, xv.y - pv.y, xv.z - pv.z, xv.w - pv.w};
            short4v h;
            #pragma unroll
            for (int j = 0; j < 4; ++j) h[j] = (short)f2bf(a[j]);
            *(short4v*)&Ah[(size_t)row * DM + c] = h;
        } else {
            const int j2 = i - NA;
            const int row = j2 / 192;
            const int c = (j2 % 192) * 4;
            const float4 wv = *(const float4*)&We[(size_t)row * DM + c];
            float a[4] = {wv.x, wv.y, wv.z, wv.w};
            short4v h;
            #pragma unroll
            for (int j = 0; j < 4; ++j) h[j] = (short)f2bf(a[j]);
            *(short4v*)&Bh[(size_t)row * DM + c] = h;
        }
    } else if (blk < PREP_BLKS + TR_BLKS) {
        const int i2 = blk - PREP_BLKS;
        const int bx = (i2 % (NS / 32)) * 32;   // s
        const int by = (i2 / (NS / 32)) * 32;   // d
        const int tx = threadIdx.x & 31;
        const int ty = threadIdx.x >> 5;        // 0..7
        #pragma unroll
        for (int r = 0; r < 32; r += 8)
            tile[ty + r][tx] = Wd[(size_t)(by + ty + r) * NS + bx + tx];
        __syncthreads();
        #pragma unroll
        for (int r = 0; r < 32; r += 8)
            WTb[(size_t)(bx + ty + r) * DM + by + tx] = f2bf(tile[tx][ty + r]);
    } else {
        const int i3 = (blk - PREP_BLKS - TR_BLKS) * 256 + threadIdx.x;
        if (i3 < NB) cnt[i3] = 0;
    }
}

// ============ bf16 MFMA encode GEMM + per-row-bucket filter epilogue ============
// Round-8 validated structure (495 us floor for this shape; six alternative
// schedules tested r8-r14 were all null or regressions).
__global__ __launch_bounds__(256) void encode_filter(
    const short* __restrict__ Ah, const short* __restrict__ Bh,
    const float* __restrict__ be,
    unsigned long long* __restrict__ cand, int* __restrict__ cnt)
{
    __shared__ __align__(16) char smem[16384];
    short* Ash = (short*)smem;
    short* Bsh = (short*)(smem + 8192);
    unsigned long long* lbuf = (unsigned long long*)smem;   // aliases staging after K-loop
    __shared__ int lcnt[128];

    const int t = threadIdx.x;
    const int l = t & 63;
    const int w = t >> 6;           // wave 0..3 -> (wm,wn) in 2x2
    const int wm = w >> 1, wn = w & 1;
    const int bm = blockIdx.y * 128;
    const int bn = blockIdx.x * 128;

    const int srow = l >> 2;                              // staging: row within 16-row chunk
    const int gsrc = (((l & 3) ^ ((l >> 2) & 3)) * 8);    // staging k-granule swizzle (r8-verified)
    const int lr = l & 15;
    const int gs8 = (((l >> 4) ^ (l & 3)) * 8);           // matching read granule

    f32x4 acc[4][4];
    #pragma unroll
    for (int m = 0; m < 4; ++m)
        #pragma unroll
        for (int n = 0; n < 4; ++n)
            acc[m][n] = f32x4{0.f, 0.f, 0.f, 0.f};

    for (int ks = 0; ks < DM; ks += 32) {
        __syncthreads();
        #pragma unroll
        for (int h = 0; h < 2; ++h) {
            const int c = w * 2 + h;            // chunk 0..7 (wave-uniform)
            const int row = c * 16 + srow;      // tile row 0..127
            __builtin_amdgcn_global_load_lds(
                (const __attribute__((address_space(1))) void*)(Ah + (size_t)(bm + row) * DM + ks + gsrc),
                (__attribute__((address_space(3))) void*)(Ash + c * 512), 16, 0, 0);
            __builtin_amdgcn_global_load_lds(
                (const __attribute__((address_space(1))) void*)(Bh + (size_t)(bn + row) * DM + ks + gsrc),
                (__attribute__((address_space(3))) void*)(Bsh + c * 512), 16, 0, 0);
        }
        __syncthreads();

        short8v a[4], b[4];
        #pragma unroll
        for (int m = 0; m < 4; ++m)
            a[m] = *(const short8v*)&Ash[(wm * 64 + m * 16 + lr) * 32 + gs8];
        #pragma unroll
        for (int n = 0; n < 4; ++n)
            b[n] = *(const short8v*)&Bsh[(wn * 64 + n * 16 + lr) * 32 + gs8];
        #pragma unroll
        for (int m = 0; m < 4; ++m)
            #pragma unroll
            for (int n = 0; n < 4; ++n)
                acc[m][n] = __builtin_amdgcn_mfma_f32_16x16x32_bf16(a[m], b[n], acc[m][n], 0, 0, 0);
    }

    // staging tiles now dead: hand the LDS to the buckets
    __syncthreads();                 // all waves' frag reads retired
    if (t < 128) lcnt[t] = 0;
    __syncthreads();                 // lcnt visible; lbuf alias safe

    // ---- stage 1: predicated per-row LDS bucket push ----
    // C/D layout: col = lane&15, row = (lane>>4)*4 + r
    #pragma unroll
    for (int n = 0; n < 4; ++n) {
        const int colg = bn + wn * 64 + n * 16 + lr;
        const float bev = be[colg];
        #pragma unroll
        for (int m = 0; m < 4; ++m) {
            const int rl0 = wm * 64 + m * 16 + (l >> 4) * 4;
            #pragma unroll
            for (int r = 0; r < 4; ++r) {
                const float v = acc[m][n][r] + bev;
                if (v >= T0F) {
                    const int rl = rl0 + r;
                    const unsigned long long e =
                        ((unsigned long long)__float_as_uint(v) << 32) | (unsigned)colg;
                    const int p = atomicAdd(&lcnt[rl], 1);
                    if (p < RCAP) {
                        lbuf[rl * RCAP + p] = e;
                    } else {
                        // lossless slow path on bucket overflow (rare)
                        const int q = atomicAdd(&cnt[bm + rl], 1);
                        if (q < CAP) cand[(size_t)(bm + rl) * CAP + q] = e;
                    }
                }
            }
        }
    }
    __syncthreads();

    // ---- stage 2: one global atomic per row, parallel copy ----
    if (t < 128) {
        int c = lcnt[t]; if (c > RCAP) c = RCAP;
        if (c > 0) {
            const int rowg = bm + t;
            const int base = atomicAdd(&cnt[rowg], c);
            for (int i = 0; i < c; ++i) {
                const int p = base + i;
                if (p < CAP) cand[(size_t)rowg * CAP + p] = lbuf[t * RCAP + i];
            }
        }
    }
}

// ============ fused top-k + full-row z write + decode (fast path) ============
// Per row: radix-select on candidate list, band-refine with exact fp32 dots,
// index-sort the K winners, write the FULL z row (coalesced zero stream then
// dword scatter; replaces the serialized memset), then decode recon in-block
// from the LDS-resident (val,idx) list (replaces the decode dispatch + tv/ti).
__global__ __launch_bounds__(256) void topk_all(
    const unsigned long long* __restrict__ cand, const int* __restrict__ cnt,
    float* __restrict__ z,
    const float* __restrict__ x, const float* __restrict__ bp,
    const float* __restrict__ We, const float* __restrict__ be,
    const unsigned short* __restrict__ WTb, const float* __restrict__ bd,
    float* __restrict__ recon, int* __restrict__ rowflag)
{
    const int row = blockIdx.x;
    const int t = threadIdx.x;
    const int l = t & 63;
    const int w = t >> 6;
    float* zr = z + (size_t)row * NS;

    const int cc = cnt[row];
    if (cc < K || cc > CAP) { if (t == 0) rowflag[row] = 1; return; }

    __shared__ unsigned ckey[CAP];
    __shared__ int      cidx[CAP];
    __shared__ unsigned hist[256];
    __shared__ int   bandi[BANDC];
    __shared__ float bexa[BANDC];
    __shared__ int   cini[K];
    __shared__ float cinf[K];
    __shared__ int   seli[K];
    __shared__ float selv[K];
    __shared__ int   osi[K];      // index-sorted winners
    __shared__ float osv[K];
    __shared__ unsigned s_prefix, s_pmask;
    __shared__ int s_need, s_cin, s_bc, s_ns;

    const unsigned long long* cr = cand + (size_t)row * CAP;
    for (int i = t; i < cc; i += 256) {
        const unsigned long long pk = cr[i];
        ckey[i] = (unsigned)(pk >> 32);          // raw f32 bits; all >= T0F > 0 -> monotonic
        cidx[i] = (int)(unsigned)(pk & 0xFFFFFFFFull);
    }
    if (t == 0) { s_prefix = 0u; s_pmask = 0u; s_need = K; s_cin = 0; s_bc = 0; s_ns = 0; }
    __syncthreads();

    // exact radix select of rank-K key (4 x 8-bit passes, LDS only)
    for (int shift = 24; shift >= 0; shift -= 8) {
        hist[t] = 0u;
        __syncthreads();
        const unsigned prefix = s_prefix, pmask = s_pmask;
        for (int c = t; c < cc; c += 256) {
            const unsigned u = ckey[c];
            if ((u & pmask) == prefix) atomicAdd(&hist[(u >> shift) & 255u], 1u);
        }
        __syncthreads();
        if (t == 0) {
            int need = s_need; unsigned cum = 0; int sel = 0;
            for (int b = 255; b >= 0; --b) {
                if (cum + hist[b] >= (unsigned)need) { sel = b; break; }
                cum += hist[b];
            }
            s_need = need - (int)cum;
            s_prefix = prefix | ((unsigned)sel << shift);
            s_pmask = pmask | (0xFFu << shift);
        }
        __syncthreads();
    }

    const float Tf = __uint_as_float(s_prefix);
    if (Tf - DELTA < T0F) { if (t == 0) rowflag[row] = 1; return; }   // band dips under pre-threshold
    const unsigned khi = __float_as_uint(Tf + DELTA);
    const unsigned klo = __float_as_uint(Tf - DELTA);

    for (int c = t; c < cc; c += 256) {
        const unsigned u = ckey[c];
        if (u > khi) {                       // certainly in true top-K
            const int p = atomicAdd(&s_cin, 1);
            if (p < K) { cini[p] = cidx[c]; cinf[p] = __uint_as_float(u); }
        } else if (u >= klo) {               // boundary band: exact comparison needed
            const int p = atomicAdd(&s_bc, 1);
            if (p < BANDC) bandi[p] = cidx[c];
        }
    }
    __syncthreads();
    const int cin  = s_cin;
    const int bc   = s_bc;
    const int nsel = K - cin;
    if (cin >= K || bc > BANDC || bc < nsel) { if (t == 0) rowflag[row] = 1; return; }

    // exact fp32 dots for band members (one wave per member, round-robin)
    const float* xr = x + (size_t)row * DM;
    for (int c = w; c < bc; c += 4) {
        const int s = bandi[c];
        const float* wr = We + (size_t)s * DM;
        float acc = 0.f;
        for (int k = l; k < DM; k += 64)
            acc = fmaf(xr[k] - bp[k], wr[k], acc);
        #pragma unroll
        for (int off = 32; off > 0; off >>= 1) acc += __shfl_xor(acc, off);
        if (l == 0) bexa[c] = acc + be[s];
    }
    __syncthreads();

    // band ranking by (exact desc, index asc); take top nsel
    if (t < bc) {
        const float myv = bexa[t];
        const int myi = bandi[t];
        int rk = 0;
        for (int j = 0; j < bc; ++j) {
            const float vj = bexa[j];
            rk += (vj > myv) || (vj == myv && bandi[j] < myi);
        }
        if (rk < nsel) {
            const int p = atomicAdd(&s_ns, 1);
            if (p < K) { seli[p] = myi; selv[p] = myv; }
        }
    }
    if (t < cin) {
        const int p = atomicAdd(&s_ns, 1);
        if (p < K) { seli[p] = cini[t]; selv[p] = cinf[t]; }
    }
    __syncthreads();
    if (s_ns != K) { if (t == 0) rowflag[row] = 1; return; }
    if (t == 0) rowflag[row] = 0;

    // index-rank sort the K winners -> deterministic scatter and decode order
    if (t < K) {
        const int myi = seli[t];
        int r = 0;
        #pragma unroll 8
        for (int j = 0; j < K; ++j) r += (seli[j] < myi);
        osi[r] = myi;
        osv[r] = selv[t];
    }

    // full-row z write: coalesced zero stream, barrier, dword scatter
    {
        const f32x4 z4 = {0.f, 0.f, 0.f, 0.f};
        f32x4* zw = (f32x4*)zr;
        for (int i = t; i < NS / 4; i += 256) zw[i] = z4;
    }
    __syncthreads();   // zero writes complete + osi/osv visible
    if (t < K) zr[osi[t]] = osv[t];

    // in-block decode: recon[row] = bd + sum_k osv[k] * WTb[osi[k]]
    if (t < 192) {
        const int d0 = t * 4;
        float4 a = *(const float4*)&bd[d0];
        #pragma unroll 4
        for (int k = 0; k < K; ++k) {
            const ushort4 wv = *(const ushort4*)(WTb + (size_t)osi[k] * DM + d0);
            const float v = osv[k];
            a.x = fmaf(v, bf2f(wv.x), a.x);
            a.y = fmaf(v, bf2f(wv.y), a.y);
            a.z = fmaf(v, bf2f(wv.z), a.z);
            a.w = fmaf(v, bf2f(wv.w), a.w);
        }
        *(float4*)&recon[(size_t)row * DM + d0] = a;
    }
}

// ============ exact self-contained fallback + row write + decode (flagged rows) ============
constexpr int XCAP = 6144;
#define XT0 0.8f

__global__ __launch_bounds__(256) void topk_exact_fb(
    float* __restrict__ z,
    const float* __restrict__ x, const float* __restrict__ bp,
    const float* __restrict__ We, const float* __restrict__ be,
    const unsigned short* __restrict__ WTb, const float* __restrict__ bd,
    float* __restrict__ recon, const int* __restrict__ rowflag)
{
    const int row = blockIdx.x;
    if (rowflag[row] == 0) return;
    const int t = threadIdx.x;
    float* zr = z + (size_t)row * NS;
    const float* xr = x + (size_t)row * DM;

    __shared__ unsigned xkey[XCAP];
    __shared__ int      xidx[XCAP];
    __shared__ unsigned hist[256];
    __shared__ int   eq[128];
    __shared__ float selv[K];
    __shared__ int   seli[K];
    __shared__ float osv[K];
    __shared__ int   osi[K];
    __shared__ unsigned s_prefix, s_pmask;
    __shared__ int s_cnt, s_need, s_eqc, s_ns;

    if (t == 0) { s_cnt = 0; s_eqc = 0; s_ns = 0; s_prefix = 0u; s_pmask = 0u; s_need = K; }
    __syncthreads();

    // stage 1: exact recompute of row, collect values >= XT0
    for (int j = t; j < NS; j += 256) {
        const float* wr = We + (size_t)j * DM;
        float acc = 0.f;
        for (int k = 0; k < DM; ++k) acc = fmaf(xr[k] - bp[k], wr[k], acc);
        const float v = acc + be[j];
        if (v >= XT0) {
            const int p = atomicAdd(&s_cnt, 1);
            if (p < XCAP) { xkey[p] = fkey(v); xidx[p] = j; }
        }
    }
    __syncthreads();
    const int cc = s_cnt;

    if (cc >= K && cc <= XCAP) {
        // --- path A: radix on LDS list of exact values ---
        for (int shift = 24; shift >= 0; shift -= 8) {
            hist[t] = 0u;
            __syncthreads();
            const unsigned prefix = s_prefix, pmask = s_pmask;
            for (int c = t; c < cc; c += 256) {
                const unsigned u = xkey[c];
                if ((u & pmask) == prefix) atomicAdd(&hist[(u >> shift) & 255u], 1u);
            }
            __syncthreads();
            if (t == 0) {
                int need = s_need; unsigned cum = 0; int sel = 0;
                for (int b = 255; b >= 0; --b) {
                    if (cum + hist[b] >= (unsigned)need) { sel = b; break; }
                    cum += hist[b];
                }
                s_need = need - (int)cum;
                s_prefix = prefix | ((unsigned)sel << shift);
                s_pmask = pmask | (0xFFu << shift);
            }
            __syncthreads();
        }
        const unsigned T = s_prefix;
        const int need = s_need;

        for (int c = t; c < cc; c += 256)
            if (xkey[c] == T) { const int p = atomicAdd(&s_eqc, 1); if (p < 128) eq[p] = xidx[c]; }
        __syncthreads();
        if (t == 0) {   // keep `need` smallest tie indices
            int nn = s_eqc < 128 ? s_eqc : 128;
            int lim = need < nn ? need : nn;
            for (int a = 0; a < lim; ++a) {
                int mi = a;
                for (int b = a + 1; b < nn; ++b) if (eq[b] < eq[mi]) mi = b;
                int tmp = eq[a]; eq[a] = eq[mi]; eq[mi] = tmp;
            }
        }
        __syncthreads();

        for (int c = t; c < cc; c += 256) {
            const unsigned u = xkey[c];
            bool take = (u > T);
            if (u == T)
                for (int a = 0; a < need; ++a) if (eq[a] == xidx[c]) { take = true; break; }
            if (take) {
                const int p = atomicAdd(&s_ns, 1);
                if (p < K) { selv[p] = key2f(u); seli[p] = xidx[c]; }
            }
        }
        __syncthreads();
    } else {
        // --- path B: guaranteed full radix with per-pass recompute ---
        for (int shift = 24; shift >= 0; shift -= 8) {
            hist[t] = 0u;
            __syncthreads();
            const unsigned prefix = s_prefix, pmask = s_pmask;
            for (int j = t; j < NS; j += 256) {
                const float* wr = We + (size_t)j * DM;
                float acc = 0.f;
                for (int k = 0; k < DM; ++k) acc = fmaf(xr[k] - bp[k], wr[k], acc);
                const unsigned u = fkey(acc + be[j]);
                if ((u & pmask) == prefix) atomicAdd(&hist[(u >> shift) & 255u], 1u);
            }
            __syncthreads();
            if (t == 0) {
                int need = s_need; unsigned cum = 0; int sel = 0;
                for (int b = 255; b >= 0; --b) {
                    if (cum + hist[b] >= (unsigned)need) { sel = b; break; }
                    cum += hist[b];
                }
                s_need = need - (int)cum;
                s_prefix = prefix | ((unsigned)sel << shift);
                s_pmask = pmask | (0xFFu << shift);
            }
            __syncthreads();
        }
        const unsigned T = s_prefix;
        const int need = s_need;

        for (int j = t; j < NS; j += 256) {
            const float* wr = We + (size_t)j * DM;
            float acc = 0.f;
            for (int k = 0; k < DM; ++k) acc = fmaf(xr[k] - bp[k], wr[k], acc);
            if (fkey(acc + be[j]) == T) { const int p = atomicAdd(&s_eqc, 1); if (p < 128) eq[p] = j; }
        }
        __syncthreads();
        if (t == 0) {
            int nn = s_eqc < 128 ? s_eqc : 128;
            int lim = need < nn ? need : nn;
            for (int a = 0; a < lim; ++a) {
                int mi = a;
                for (int b = a + 1; b < nn; ++b) if (eq[b] < eq[mi]) mi = b;
                int tmp = eq[a]; eq[a] = eq[mi]; eq[mi] = tmp;
            }
        }
        __syncthreads();

        for (int j = t; j < NS; j += 256) {
            const float* wr = We + (size_t)j * DM;
            float acc = 0.f;
            for (int k = 0; k < DM; ++k) acc = fmaf(xr[k] - bp[k], wr[k], acc);
            const float v = acc + be[j];
            const unsigned u = fkey(v);
            bool take = (u > T);
            if (u == T)
                for (int a = 0; a < need; ++a) if (eq[a] == j) { take = true; break; }
            if (take) {
                const int p = atomicAdd(&s_ns, 1);
                if (p < K) { selv[p] = v; seli[p] = j; }
            }
        }
        __syncthreads();
    }

    const int ns = s_ns < K ? s_ns : K;
    // index-rank sort winners (deterministic), pad tail with zeros
    if (t < K) { osi[t] = NS; osv[t] = 0.f; }   // inert defaults if ns < K
    __syncthreads();
    if (t < ns) {
        const int myi = seli[t];
        int r = 0;
        for (int j = 0; j < ns; ++j) r += (seli[j] < myi);
        osi[r] = myi;
        osv[r] = selv[t];
    }

    // full-row z write + scatter
    {
        const f32x4 z4 = {0.f, 0.f, 0.f, 0.f};
        f32x4* zw = (f32x4*)zr;
        for (int i = t; i < NS / 4; i += 256) zw[i] = z4;
    }
    __syncthreads();
    if (t < ns) zr[osi[t]] = osv[t];

    // in-block decode (osi[k]=NS entries contribute 0 via osv=0; guard the gather)
    if (t < 192) {
        const int d0 = t * 4;
        float4 a = *(const float4*)&bd[d0];
        for (int k = 0; k < K; ++k) {
            const int s = (osi[k] < NS) ? osi[k] : 0;
            const ushort4 wv = *(const ushort4*)(WTb + (size_t)s * DM + d0);
            const float v = osv[k];
            a.x = fmaf(v, bf2f(wv.x), a.x);
            a.y = fmaf(v, bf2f(wv.y), a.y);
            a.z = fmaf(v, bf2f(wv.z), a.z);
            a.w = fmaf(v, bf2f(wv.w), a.w);
        }
        *(float4*)&recon[(size_t)row * DM + d0] = a;
    }
}

// ===================== small-ws legacy path (round-1, validated) =====================
#define BM 128
#define BN 128
#define BK 16

__global__ __launch_bounds__(256) void encode_gemm(
    const float* __restrict__ x, const float* __restrict__ We,
    const float* __restrict__ be, const float* __restrict__ bp,
    float* __restrict__ z)
{
    __shared__ __align__(16) float As[BK][BM + 4];
    __shared__ __align__(16) float Bs[BK][BN + 4];

    const int t  = threadIdx.x;
    const int bm = blockIdx.y * BM;
    const int bn = blockIdx.x * BN;
    const int tm = (t / 16) * 8;
    const int tn = (t % 16) * 8;

    float acc[8][8] = {};

    for (int k0 = 0; k0 < DM; k0 += BK) {
        #pragma unroll
        for (int h = 0; h < 2; ++h) {
            const int q  = t + h * 256;
            const int m  = q >> 2;
            const int kq = (q & 3) * 4;
            const float4 av = *(const float4*)&x[(size_t)(bm + m) * DM + k0 + kq];
            const float4 pv = *(const float4*)&bp[k0 + kq];
            As[kq + 0][m] = av.x - pv.x;
            As[kq + 1][m] = av.y - pv.y;
            As[kq + 2][m] = av.z - pv.z;
            As[kq + 3][m] = av.w - pv.w;
            const float4 bv = *(const float4*)&We[(size_t)(bn + m) * DM + k0 + kq];
            Bs[kq + 0][m] = bv.x;
            Bs[kq + 1][m] = bv.y;
            Bs[kq + 2][m] = bv.z;
            Bs[kq + 3][m] = bv.w;
        }
        __syncthreads();

        #pragma unroll
        for (int kk = 0; kk < BK; ++kk) {
            float a[8], b[8];
            *(float4*)&a[0] = *(const float4*)&As[kk][tm];
            *(float4*)&a[4] = *(const float4*)&As[kk][tm + 4];
            *(float4*)&b[0] = *(const float4*)&Bs[kk][tn];
            *(float4*)&b[4] = *(const float4*)&Bs[kk][tn + 4];
            #pragma unroll
            for (int i = 0; i < 8; ++i)
                #pragma unroll
                for (int j = 0; j < 8; ++j)
                    acc[i][j] = fmaf(a[i], b[j], acc[i][j]);
        }
        __syncthreads();
    }

    float4 be0 = *(const float4*)&be[bn + tn];
    float4 be1 = *(const float4*)&be[bn + tn + 4];
    #pragma unroll
    for (int i = 0; i < 8; ++i) {
        const size_t rowoff = (size_t)(bm + tm + i) * NS + bn + tn;
        float4 c0, c1;
        c0.x = acc[i][0] + be0.x; c0.y = acc[i][1] + be0.y;
        c0.z = acc[i][2] + be0.z; c0.w = acc[i][3] + be0.w;
        c1.x = acc[i][4] + be1.x; c1.y = acc[i][5] + be1.y;
        c1.z = acc[i][6] + be1.z; c1.w = acc[i][7] + be1.w;
        *(float4*)&z[rowoff]     = c0;
        *(float4*)&z[rowoff + 4] = c1;
    }
}

__global__ __launch_bounds__(256) void topk_kernel(
    float* __restrict__ z, float* __restrict__ tv, int* __restrict__ ti)
{
    const int row = blockIdx.x;
    float* zr = z + (size_t)row * NS;
    const int t = threadIdx.x;

    __shared__ unsigned hist[256];
    __shared__ unsigned s_prefix, s_pmask;
    __shared__ int s_need;
    __shared__ int eqidx[128];
    __shared__ int eqcnt, outcnt;
    __shared__ float osv[K];
    __shared__ int   osi[K];

    if (t == 0) { s_prefix = 0u; s_pmask = 0u; s_need = K; eqcnt = 0; outcnt = 0; }
    __syncthreads();

    for (int shift = 24; shift >= 0; shift -= 8) {
        hist[t] = 0u;
        __syncthreads();
        const unsigned prefix = s_prefix, pmask = s_pmask;
        for (int i = t; i < NS; i += 256) {
            unsigned u = fkey(zr[i]);
            if ((u & pmask) == prefix) atomicAdd(&hist[(u >> shift) & 255u], 1u);
        }
        __syncthreads();
        if (t == 0) {
            int need = s_need;
            unsigned cum = 0; int sel = 0;
            for (int b = 255; b >= 0; --b) {
                if (cum + hist[b] >= (unsigned)need) { sel = b; break; }
                cum += hist[b];
            }
            s_need   = need - (int)cum;
            s_prefix = prefix | ((unsigned)sel << shift);
            s_pmask  = pmask | (0xFFu << shift);
        }
        __syncthreads();
    }

    const unsigned T = s_prefix;
    const int need = s_need;

    for (int i = t; i < NS; i += 256) {
        if (fkey(zr[i]) == T) {
            int p = atomicAdd(&eqcnt, 1);
            if (p < 128) eqidx[p] = i;
        }
    }
    __syncthreads();
    if (t == 0) {
        int nn = eqcnt < 128 ? eqcnt : 128;
        int lim = need < nn ? need : nn;
        for (int a = 0; a < lim; ++a) {
            int mi = a;
            for (int b = a + 1; b < nn; ++b) if (eqidx[b] < eqidx[mi]) mi = b;
            int tmp = eqidx[a]; eqidx[a] = eqidx[mi]; eqidx[mi] = tmp;
        }
    }
    __syncthreads();

    for (int i = t; i < NS; i += 256) {
        const float v = zr[i];
        const unsigned u = fkey(v);
        bool take = (u > T);
        if (u == T) {
            for (int a = 0; a < need; ++a) if (eqidx[a] == i) { take = true; break; }
        }
        if (take) {
            int p = atomicAdd(&outcnt, 1);
            if (p < K) { osv[p] = v; osi[p] = i; }
        } else {
            zr[i] = 0.0f;
        }
    }
    __syncthreads();

    if (tv != nullptr && t < K) {
        const int   myi = osi[t];
        const float myv = osv[t];
        int r = 0;
        #pragma unroll 8
        for (int j = 0; j < K; ++j) r += (osi[j] < myi);
        tv[(size_t)row * K + r] = myv;
        ti[(size_t)row * K + r] = myi;
    }
}

__global__ __launch_bounds__(256) void decode_nt(
    const float* __restrict__ tv, const int* __restrict__ ti,
    const float* __restrict__ Wd, const float* __restrict__ bd,
    float* __restrict__ recon)
{
    const int row = blockIdx.x;
    const int t = threadIdx.x;
    __shared__ float sv[K];
    __shared__ int   si[K];
    if (t < K) { sv[t] = tv[(size_t)row * K + t]; si[t] = ti[(size_t)row * K + t]; }
    __syncthreads();
    float a0 = bd[t], a1 = bd[t + 256], a2 = bd[t + 512];
    for (int k = 0; k < K; ++k) {
        const float v = sv[k];
        const int s = si[k];
        a0 = fmaf(v, Wd[(size_t)t * NS + s],         a0);
        a1 = fmaf(v, Wd[(size_t)(t + 256) * NS + s], a1);
        a2 = fmaf(v, Wd[(size_t)(t + 512) * NS + s], a2);
    }
    float* rr = recon + (size_t)row * DM;
    rr[t] = a0; rr[t + 256] = a1; rr[t + 512] = a2;
}

__global__ __launch_bounds__(256) void decode_scan(
    const float* __restrict__ z, const float* __restrict__ Wd,
    const float* __restrict__ bd, float* __restrict__ recon)
{
    constexpr int CAP2 = 96;
    const int row = blockIdx.x;
    const int t = threadIdx.x;
    __shared__ float sv[CAP2], sv2[CAP2];
    __shared__ int   si[CAP2], si2[CAP2];
    __shared__ int cnt;
    if (t == 0) cnt = 0;
    __syncthreads();
    const float* zr = z + (size_t)row * NS;
    for (int i = t; i < NS; i += 256) {
        float v = zr[i];
        if (v != 0.0f) { int p = atomicAdd(&cnt, 1); if (p < CAP2) { sv[p] = v; si[p] = i; } }
    }
    __syncthreads();
    const int n = cnt < CAP2 ? cnt : CAP2;
    if (t < n) {
        int myi = si[t]; int r = 0;
        for (int j = 0; j < n; ++j) r += (si[j] < myi);
        sv2[r] = sv[t]; si2[r] = myi;
    }
    __syncthreads();
    float a0 = bd[t], a1 = bd[t + 256], a2 = bd[t + 512];
    for (int k = 0; k < n; ++k) {
        const float v = sv2[k];
        const int s = si2[k];
        a0 = fmaf(v, Wd[(size_t)t * NS + s],         a0);
        a1 = fmaf(v, Wd[(size_t)(t + 256) * NS + s], a1);
        a2 = fmaf(v, Wd[(size_t)(t + 512) * NS + s], a2);
    }
    float* rr = recon + (size_t)row * DM;
    rr[t] = a0; rr[t + 256] = a1; rr[t + 512] = a2;
}

// ===================== launch =====================
extern "C" void kernel_launch(void* const* d_in, const int* in_sizes, int n_in,
                              void* d_out, int out_size, void* d_ws, size_t ws_size,
                              hipStream_t stream) {
    const float* x  = (const float*)d_in[0];
    const float* We = (const float*)d_in[1];
    const float* be = (const float*)d_in[2];
    const float* Wd = (const float*)d_in[3];
    const float* bd = (const float*)d_in[4];
    const float* bp = (const float*)d_in[5];

    float* recon = (float*)d_out;                       // [8192][768]
    float* zs    = recon + (size_t)NB * DM;             // [8192][24576] (z_sparse)

    const size_t szAh   = (size_t)NB * DM * 2;          // 12.6 MB
    const size_t szBh   = (size_t)NS * DM * 2;          // 37.7 MB
    const size_t szWTb  = (size_t)NS * DM * 2;          // 37.7 MB
    const size_t szCand = (size_t)NB * CAP * 8;         // 67.1 MB
    const size_t szCnt  = (size_t)NB * 4;               // 32 KB
    const size_t szFL   = (size_t)NB * 4;               // 32 KB
    const size_t need_fast = szAh + szBh + szWTb + szCand + szCnt + szFL;  // ~155 MB (r13/r14 proven)

    if (ws_size >= need_fast) {
        char* p = (char*)d_ws;
        short* Ah = (short*)p;                         p += szAh;
        short* Bh = (short*)p;                         p += szBh;
        unsigned short* WTb = (unsigned short*)p;      p += szWTb;
        unsigned long long* cand = (unsigned long long*)p;  p += szCand;
        int*   cnt = (int*)p;                          p += szCnt;
        int*   fl  = (int*)p;

        prep_all<<<PREP_BLKS + TR_BLKS + CNT_BLKS, 256, 0, stream>>>(x, bp, We, Ah, Bh, Wd, WTb, cnt);
        encode_filter<<<dim3(NS / 128, NB / 128), 256, 0, stream>>>(Ah, Bh, be, cand, cnt);
        topk_all<<<NB, 256, 0, stream>>>(cand, cnt, zs, x, bp, We, be, WTb, bd, recon, fl);
        topk_exact_fb<<<NB, 256, 0, stream>>>(zs, x, bp, We, be, WTb, bd, recon, fl);
    } else {
        const size_t szTV = (size_t)NB * K * 4;
        const size_t szTI = (size_t)NB * K * 4;
        const size_t need_small = szTV + szTI;
        float* tv = (float*)d_ws;
        int*   ti = (int*)((char*)d_ws + szTV);

        dim3 gg(NS / BN, NB / BM);
        encode_gemm<<<gg, 256, 0, stream>>>(x, We, be, bp, zs);

        if (ws_size >= need_small) {
            topk_kernel<<<NB, 256, 0, stream>>>(zs, tv, ti);
            decode_nt<<<NB, 256, 0, stream>>>(tv, ti, Wd, bd, recon);
        } else {
            topk_kernel<<<NB, 256, 0, stream>>>(zs, nullptr, nullptr);
            decode_scan<<<NB, 256, 0, stream>>>(zs, Wd, bd, recon);
        }
    }
}

// Round 17
// 832.694 us; speedup vs baseline: 1.9320x; 1.1241x over previous
//
#include <hip/hip_runtime.h>
#include <hip/hip_bf16.h>

// Problem constants (fixed by the reference)
constexpr int DM = 768;     // d_model (GEMM K dim)
constexpr int NS = 24576;   // d_sae
constexpr int NB = 8192;    // batch
constexpr int K  = 64;      // top-k

constexpr int CAP   = 1024;  // per-row candidate capacity (expected ~462, +26 sigma)
constexpr int BANDC = 256;   // refinement band capacity
constexpr int RCAP  = 16;    // per-row per-block LDS bucket (expected 2.4; lossless overflow)
#define T0F   1.2f           // candidate pre-threshold (guarded; fallback if violated)
#define DELTA 0.015f         // selection uncertainty band >= 2*bf16-GEMM error (~0.007)

typedef __attribute__((ext_vector_type(8))) short short8v;
typedef __attribute__((ext_vector_type(4))) short short4v;
typedef __attribute__((ext_vector_type(4))) float f32x4;

__device__ __forceinline__ unsigned short f2bf(float f) {
    unsigned u = __float_as_uint(f);
    u += 0x7FFFu + ((u >> 16) & 1u);          // RNE, finite inputs only
    return (unsigned short)(u >> 16);
}
__device__ __forceinline__ float bf2f(unsigned short h) {
    return __uint_as_float(((unsigned)h) << 16);
}
__device__ __forceinline__ unsigned fkey(float f) {
    unsigned u = __float_as_uint(f);
    return (u & 0x80000000u) ? ~u : (u | 0x80000000u);   // monotonic ascending, all floats
}
__device__ __forceinline__ float key2f(unsigned k) {
    unsigned u = (k & 0x80000000u) ? (k & 0x7FFFFFFFu) : ~k;
    return __uint_as_float(u);
}

// ============ fused prep: bf16 A+B convert, W_dec transpose, cnt zeroing ============
constexpr int PREP_BLKS = (NB * 192 + NS * 192) / 256;   // 24576
constexpr int TR_BLKS   = (NS / 32) * (DM / 32);         // 18432
constexpr int CNT_BLKS  = NB / 256;                      // 32

__global__ __launch_bounds__(256) void prep_all(
    const float* __restrict__ x, const float* __restrict__ bp,
    const float* __restrict__ We, short* __restrict__ Ah, short* __restrict__ Bh,
    const float* __restrict__ Wd, unsigned short* __restrict__ WTb,
    int* __restrict__ cnt)
{
    __shared__ float tile[32][33];
    const int blk = blockIdx.x;
    if (blk < PREP_BLKS) {
        const int i = blk * 256 + threadIdx.x;
        constexpr int NA = NB * 192;                 // A-region float4 count
        if (i < NA) {
            const int row = i / 192;
            const int c = (i % 192) * 4;
            const float4 xv = *(const float4*)&x[(size_t)row * DM + c];
            const float4 pv = *(const float4*)&bp[c];
            float a[4] = {xv.x - pv.x, xv.y - pv.y, xv.z - pv.z, xv.w - pv.w};
            short4v h;
            #pragma unroll
            for (int j = 0; j < 4; ++j) h[j] = (short)f2bf(a[j]);
            *(short4v*)&Ah[(size_t)row * DM + c] = h;
        } else {
            const int j2 = i - NA;
            const int row = j2 / 192;
            const int c = (j2 % 192) * 4;
            const float4 wv = *(const float4*)&We[(size_t)row * DM + c];
            float a[4] = {wv.x, wv.y, wv.z, wv.w};
            short4v h;
            #pragma unroll
            for (int j = 0; j < 4; ++j) h[j] = (short)f2bf(a[j]);
            *(short4v*)&Bh[(size_t)row * DM + c] = h;
        }
    } else if (blk < PREP_BLKS + TR_BLKS) {
        const int i2 = blk - PREP_BLKS;
        const int bx = (i2 % (NS / 32)) * 32;   // s
        const int by = (i2 / (NS / 32)) * 32;   // d
        const int tx = threadIdx.x & 31;
        const int ty = threadIdx.x >> 5;        // 0..7
        #pragma unroll
        for (int r = 0; r < 32; r += 8)
            tile[ty + r][tx] = Wd[(size_t)(by + ty + r) * NS + bx + tx];
        __syncthreads();
        #pragma unroll
        for (int r = 0; r < 32; r += 8)
            WTb[(size_t)(bx + ty + r) * DM + by + tx] = f2bf(tile[tx][ty + r]);
    } else {
        const int i3 = (blk - PREP_BLKS - TR_BLKS) * 256 + threadIdx.x;
        if (i3 < NB) cnt[i3] = 0;
    }
}

// ============ bf16 MFMA encode GEMM + per-row-bucket filter epilogue ============
// Round-8 validated structure (495 us floor for this shape; six alternative
// schedules tested r8-r14 were all null or regressions).
__global__ __launch_bounds__(256) void encode_filter(
    const short* __restrict__ Ah, const short* __restrict__ Bh,
    const float* __restrict__ be,
    unsigned long long* __restrict__ cand, int* __restrict__ cnt)
{
    __shared__ __align__(16) char smem[16384];
    short* Ash = (short*)smem;
    short* Bsh = (short*)(smem + 8192);
    unsigned long long* lbuf = (unsigned long long*)smem;   // aliases staging after K-loop
    __shared__ int lcnt[128];

    const int t = threadIdx.x;
    const int l = t & 63;
    const int w = t >> 6;           // wave 0..3 -> (wm,wn) in 2x2
    const int wm = w >> 1, wn = w & 1;
    const int bm = blockIdx.y * 128;
    const int bn = blockIdx.x * 128;

    const int srow = l >> 2;                              // staging: row within 16-row chunk
    const int gsrc = (((l & 3) ^ ((l >> 2) & 3)) * 8);    // staging k-granule swizzle (r8-verified)
    const int lr = l & 15;
    const int gs8 = (((l >> 4) ^ (l & 3)) * 8);           // matching read granule

    f32x4 acc[4][4];
    #pragma unroll
    for (int m = 0; m < 4; ++m)
        #pragma unroll
        for (int n = 0; n < 4; ++n)
            acc[m][n] = f32x4{0.f, 0.f, 0.f, 0.f};

    for (int ks = 0; ks < DM; ks += 32) {
        __syncthreads();
        #pragma unroll
        for (int h = 0; h < 2; ++h) {
            const int c = w * 2 + h;            // chunk 0..7 (wave-uniform)
            const int row = c * 16 + srow;      // tile row 0..127
            __builtin_amdgcn_global_load_lds(
                (const __attribute__((address_space(1))) void*)(Ah + (size_t)(bm + row) * DM + ks + gsrc),
                (__attribute__((address_space(3))) void*)(Ash + c * 512), 16, 0, 0);
            __builtin_amdgcn_global_load_lds(
                (const __attribute__((address_space(1))) void*)(Bh + (size_t)(bn + row) * DM + ks + gsrc),
                (__attribute__((address_space(3))) void*)(Bsh + c * 512), 16, 0, 0);
        }
        __syncthreads();

        short8v a[4], b[4];
        #pragma unroll
        for (int m = 0; m < 4; ++m)
            a[m] = *(const short8v*)&Ash[(wm * 64 + m * 16 + lr) * 32 + gs8];
        #pragma unroll
        for (int n = 0; n < 4; ++n)
            b[n] = *(const short8v*)&Bsh[(wn * 64 + n * 16 + lr) * 32 + gs8];
        #pragma unroll
        for (int m = 0; m < 4; ++m)
            #pragma unroll
            for (int n = 0; n < 4; ++n)
                acc[m][n] = __builtin_amdgcn_mfma_f32_16x16x32_bf16(a[m], b[n], acc[m][n], 0, 0, 0);
    }

    // staging tiles now dead: hand the LDS to the buckets
    __syncthreads();                 // all waves' frag reads retired
    if (t < 128) lcnt[t] = 0;
    __syncthreads();                 // lcnt visible; lbuf alias safe

    // ---- stage 1: predicated per-row LDS bucket push ----
    // C/D layout: col = lane&15, row = (lane>>4)*4 + r
    #pragma unroll
    for (int n = 0; n < 4; ++n) {
        const int colg = bn + wn * 64 + n * 16 + lr;
        const float bev = be[colg];
        #pragma unroll
        for (int m = 0; m < 4; ++m) {
            const int rl0 = wm * 64 + m * 16 + (l >> 4) * 4;
            #pragma unroll
            for (int r = 0; r < 4; ++r) {
                const float v = acc[m][n][r] + bev;
                if (v >= T0F) {
                    const int rl = rl0 + r;
                    const unsigned long long e =
                        ((unsigned long long)__float_as_uint(v) << 32) | (unsigned)colg;
                    const int p = atomicAdd(&lcnt[rl], 1);
                    if (p < RCAP) {
                        lbuf[rl * RCAP + p] = e;
                    } else {
                        // lossless slow path on bucket overflow (rare)
                        const int q = atomicAdd(&cnt[bm + rl], 1);
                        if (q < CAP) cand[(size_t)(bm + rl) * CAP + q] = e;
                    }
                }
            }
        }
    }
    __syncthreads();

    // ---- stage 2: one global atomic per row, parallel copy ----
    if (t < 128) {
        int c = lcnt[t]; if (c > RCAP) c = RCAP;
        if (c > 0) {
            const int rowg = bm + t;
            const int base = atomicAdd(&cnt[rowg], c);
            for (int i = 0; i < c; ++i) {
                const int p = base + i;
                if (p < CAP) cand[(size_t)rowg * CAP + p] = lbuf[t * RCAP + i];
            }
        }
    }
}

// ============ fused top-k + full-row z write + decode (fast path) ============
// z zero-fill is issued EARLY (right after the cand stage-in, nontemporal) so
// the 96 KB/row write stream completes underneath the LDS radix + band-dot
// phases; the pre-scatter __syncthreads (vmcnt drain) orders fill->scatter.
// NT stores keep the 805 MB write sweep from evicting cand/We/x/WTb in L2.
__global__ __launch_bounds__(256) void topk_all(
    const unsigned long long* __restrict__ cand, const int* __restrict__ cnt,
    float* __restrict__ z,
    const float* __restrict__ x, const float* __restrict__ bp,
    const float* __restrict__ We, const float* __restrict__ be,
    const unsigned short* __restrict__ WTb, const float* __restrict__ bd,
    float* __restrict__ recon, int* __restrict__ rowflag)
{
    const int row = blockIdx.x;
    const int t = threadIdx.x;
    const int l = t & 63;
    const int w = t >> 6;
    float* zr = z + (size_t)row * NS;

    const int cc = cnt[row];
    if (cc < K || cc > CAP) { if (t == 0) rowflag[row] = 1; return; }

    __shared__ unsigned ckey[CAP];
    __shared__ int      cidx[CAP];
    __shared__ unsigned hist[256];
    __shared__ int   bandi[BANDC];
    __shared__ float bexa[BANDC];
    __shared__ int   cini[K];
    __shared__ float cinf[K];
    __shared__ int   seli[K];
    __shared__ float selv[K];
    __shared__ int   osi[K];      // index-sorted winners
    __shared__ float osv[K];
    __shared__ unsigned s_prefix, s_pmask;
    __shared__ int s_need, s_cin, s_bc, s_ns;

    const unsigned long long* cr = cand + (size_t)row * CAP;
    for (int i = t; i < cc; i += 256) {
        const unsigned long long pk = cr[i];
        ckey[i] = (unsigned)(pk >> 32);          // raw f32 bits; all >= T0F > 0 -> monotonic
        cidx[i] = (int)(unsigned)(pk & 0xFFFFFFFFull);
    }

    // early nontemporal zero-fill: completes under the radix/band phases
    {
        const f32x4 z4 = {0.f, 0.f, 0.f, 0.f};
        f32x4* zw = (f32x4*)zr;
        for (int i = t; i < NS / 4; i += 256)
            __builtin_nontemporal_store(z4, &zw[i]);
    }

    if (t == 0) { s_prefix = 0u; s_pmask = 0u; s_need = K; s_cin = 0; s_bc = 0; s_ns = 0; }
    __syncthreads();

    // exact radix select of rank-K key (4 x 8-bit passes, LDS only)
    for (int shift = 24; shift >= 0; shift -= 8) {
        hist[t] = 0u;
        __syncthreads();
        const unsigned prefix = s_prefix, pmask = s_pmask;
        for (int c = t; c < cc; c += 256) {
            const unsigned u = ckey[c];
            if ((u & pmask) == prefix) atomicAdd(&hist[(u >> shift) & 255u], 1u);
        }
        __syncthreads();
        if (t == 0) {
            int need = s_need; unsigned cum = 0; int sel = 0;
            for (int b = 255; b >= 0; --b) {
                if (cum + hist[b] >= (unsigned)need) { sel = b; break; }
                cum += hist[b];
            }
            s_need = need - (int)cum;
            s_prefix = prefix | ((unsigned)sel << shift);
            s_pmask = pmask | (0xFFu << shift);
        }
        __syncthreads();
    }

    const float Tf = __uint_as_float(s_prefix);
    if (Tf - DELTA < T0F) { if (t == 0) rowflag[row] = 1; return; }   // band dips under pre-threshold
    const unsigned khi = __float_as_uint(Tf + DELTA);
    const unsigned klo = __float_as_uint(Tf - DELTA);

    for (int c = t; c < cc; c += 256) {
        const unsigned u = ckey[c];
        if (u > khi) {                       // certainly in true top-K
            const int p = atomicAdd(&s_cin, 1);
            if (p < K) { cini[p] = cidx[c]; cinf[p] = __uint_as_float(u); }
        } else if (u >= klo) {               // boundary band: exact comparison needed
            const int p = atomicAdd(&s_bc, 1);
            if (p < BANDC) bandi[p] = cidx[c];
        }
    }
    __syncthreads();
    const int cin  = s_cin;
    const int bc   = s_bc;
    const int nsel = K - cin;
    if (cin >= K || bc > BANDC || bc < nsel) { if (t == 0) rowflag[row] = 1; return; }

    // exact fp32 dots for band members (one wave per member, round-robin)
    const float* xr = x + (size_t)row * DM;
    for (int c = w; c < bc; c += 4) {
        const int s = bandi[c];
        const float* wr = We + (size_t)s * DM;
        float acc = 0.f;
        for (int k = l; k < DM; k += 64)
            acc = fmaf(xr[k] - bp[k], wr[k], acc);
        #pragma unroll
        for (int off = 32; off > 0; off >>= 1) acc += __shfl_xor(acc, off);
        if (l == 0) bexa[c] = acc + be[s];
    }
    __syncthreads();

    // band ranking by (exact desc, index asc); take top nsel
    if (t < bc) {
        const float myv = bexa[t];
        const int myi = bandi[t];
        int rk = 0;
        for (int j = 0; j < bc; ++j) {
            const float vj = bexa[j];
            rk += (vj > myv) || (vj == myv && bandi[j] < myi);
        }
        if (rk < nsel) {
            const int p = atomicAdd(&s_ns, 1);
            if (p < K) { seli[p] = myi; selv[p] = myv; }
        }
    }
    if (t < cin) {
        const int p = atomicAdd(&s_ns, 1);
        if (p < K) { seli[p] = cini[t]; selv[p] = cinf[t]; }
    }
    __syncthreads();
    if (s_ns != K) { if (t == 0) rowflag[row] = 1; return; }
    if (t == 0) rowflag[row] = 0;

    // index-rank sort the K winners -> deterministic scatter and decode order
    if (t < K) {
        const int myi = seli[t];
        int r = 0;
        #pragma unroll 8
        for (int j = 0; j < K; ++j) r += (seli[j] < myi);
        osi[r] = myi;
        osv[r] = selv[t];
    }
    __syncthreads();   // fill stores drained (vmcnt 0) + osi/osv visible
    if (t < K) __builtin_nontemporal_store(osv[t], &zr[osi[t]]);

    // in-block decode: recon[row] = bd + sum_k osv[k] * WTb[osi[k]]
    if (t < 192) {
        const int d0 = t * 4;
        f32x4 a = *(const f32x4*)&bd[d0];
        #pragma unroll 4
        for (int k = 0; k < K; ++k) {
            const ushort4 wv = *(const ushort4*)(WTb + (size_t)osi[k] * DM + d0);
            const float v = osv[k];
            a.x = fmaf(v, bf2f(wv.x), a.x);
            a.y = fmaf(v, bf2f(wv.y), a.y);
            a.z = fmaf(v, bf2f(wv.z), a.z);
            a.w = fmaf(v, bf2f(wv.w), a.w);
        }
        __builtin_nontemporal_store(a, (f32x4*)&recon[(size_t)row * DM + d0]);
    }
}

// ============ exact self-contained fallback + row write + decode (flagged rows) ============
constexpr int XCAP = 6144;
#define XT0 0.8f

__global__ __launch_bounds__(256) void topk_exact_fb(
    float* __restrict__ z,
    const float* __restrict__ x, const float* __restrict__ bp,
    const float* __restrict__ We, const float* __restrict__ be,
    const unsigned short* __restrict__ WTb, const float* __restrict__ bd,
    float* __restrict__ recon, const int* __restrict__ rowflag)
{
    const int row = blockIdx.x;
    if (rowflag[row] == 0) return;
    const int t = threadIdx.x;
    float* zr = z + (size_t)row * NS;
    const float* xr = x + (size_t)row * DM;

    __shared__ unsigned xkey[XCAP];
    __shared__ int      xidx[XCAP];
    __shared__ unsigned hist[256];
    __shared__ int   eq[128];
    __shared__ float selv[K];
    __shared__ int   seli[K];
    __shared__ float osv[K];
    __shared__ int   osi[K];
    __shared__ unsigned s_prefix, s_pmask;
    __shared__ int s_cnt, s_need, s_eqc, s_ns;

    if (t == 0) { s_cnt = 0; s_eqc = 0; s_ns = 0; s_prefix = 0u; s_pmask = 0u; s_need = K; }
    __syncthreads();

    // stage 1: exact recompute of row, collect values >= XT0
    for (int j = t; j < NS; j += 256) {
        const float* wr = We + (size_t)j * DM;
        float acc = 0.f;
        for (int k = 0; k < DM; ++k) acc = fmaf(xr[k] - bp[k], wr[k], acc);
        const float v = acc + be[j];
        if (v >= XT0) {
            const int p = atomicAdd(&s_cnt, 1);
            if (p < XCAP) { xkey[p] = fkey(v); xidx[p] = j; }
        }
    }
    __syncthreads();
    const int cc = s_cnt;

    if (cc >= K && cc <= XCAP) {
        // --- path A: radix on LDS list of exact values ---
        for (int shift = 24; shift >= 0; shift -= 8) {
            hist[t] = 0u;
            __syncthreads();
            const unsigned prefix = s_prefix, pmask = s_pmask;
            for (int c = t; c < cc; c += 256) {
                const unsigned u = xkey[c];
                if ((u & pmask) == prefix) atomicAdd(&hist[(u >> shift) & 255u], 1u);
            }
            __syncthreads();
            if (t == 0) {
                int need = s_need; unsigned cum = 0; int sel = 0;
                for (int b = 255; b >= 0; --b) {
                    if (cum + hist[b] >= (unsigned)need) { sel = b; break; }
                    cum += hist[b];
                }
                s_need = need - (int)cum;
                s_prefix = prefix | ((unsigned)sel << shift);
                s_pmask = pmask | (0xFFu << shift);
            }
            __syncthreads();
        }
        const unsigned T = s_prefix;
        const int need = s_need;

        for (int c = t; c < cc; c += 256)
            if (xkey[c] == T) { const int p = atomicAdd(&s_eqc, 1); if (p < 128) eq[p] = xidx[c]; }
        __syncthreads();
        if (t == 0) {   // keep `need` smallest tie indices
            int nn = s_eqc < 128 ? s_eqc : 128;
            int lim = need < nn ? need : nn;
            for (int a = 0; a < lim; ++a) {
                int mi = a;
                for (int b = a + 1; b < nn; ++b) if (eq[b] < eq[mi]) mi = b;
                int tmp = eq[a]; eq[a] = eq[mi]; eq[mi] = tmp;
            }
        }
        __syncthreads();

        for (int c = t; c < cc; c += 256) {
            const unsigned u = xkey[c];
            bool take = (u > T);
            if (u == T)
                for (int a = 0; a < need; ++a) if (eq[a] == xidx[c]) { take = true; break; }
            if (take) {
                const int p = atomicAdd(&s_ns, 1);
                if (p < K) { selv[p] = key2f(u); seli[p] = xidx[c]; }
            }
        }
        __syncthreads();
    } else {
        // --- path B: guaranteed full radix with per-pass recompute ---
        for (int shift = 24; shift >= 0; shift -= 8) {
            hist[t] = 0u;
            __syncthreads();
            const unsigned prefix = s_prefix, pmask = s_pmask;
            for (int j = t; j < NS; j += 256) {
                const float* wr = We + (size_t)j * DM;
                float acc = 0.f;
                for (int k = 0; k < DM; ++k) acc = fmaf(xr[k] - bp[k], wr[k], acc);
                const unsigned u = fkey(acc + be[j]);
                if ((u & pmask) == prefix) atomicAdd(&hist[(u >> shift) & 255u], 1u);
            }
            __syncthreads();
            if (t == 0) {
                int need = s_need; unsigned cum = 0; int sel = 0;
                for (int b = 255; b >= 0; --b) {
                    if (cum + hist[b] >= (unsigned)need) { sel = b; break; }
                    cum += hist[b];
                }
                s_need = need - (int)cum;
                s_prefix = prefix | ((unsigned)sel << shift);
                s_pmask = pmask | (0xFFu << shift);
            }
            __syncthreads();
        }
        const unsigned T = s_prefix;
        const int need = s_need;

        for (int j = t; j < NS; j += 256) {
            const float* wr = We + (size_t)j * DM;
            float acc = 0.f;
            for (int k = 0; k < DM; ++k) acc = fmaf(xr[k] - bp[k], wr[k], acc);
            if (fkey(acc + be[j]) == T) { const int p = atomicAdd(&s_eqc, 1); if (p < 128) eq[p] = j; }
        }
        __syncthreads();
        if (t == 0) {
            int nn = s_eqc < 128 ? s_eqc : 128;
            int lim = need < nn ? need : nn;
            for (int a = 0; a < lim; ++a) {
                int mi = a;
                for (int b = a + 1; b < nn; ++b) if (eq[b] < eq[mi]) mi = b;
                int tmp = eq[a]; eq[a] = eq[mi]; eq[mi] = tmp;
            }
        }
        __syncthreads();

        for (int j = t; j < NS; j += 256) {
            const float* wr = We + (size_t)j * DM;
            float acc = 0.f;
            for (int k = 0; k < DM; ++k) acc = fmaf(xr[k] - bp[k], wr[k], acc);
            const float v = acc + be[j];
            const unsigned u = fkey(v);
            bool take = (u > T);
            if (u == T)
                for (int a = 0; a < need; ++a) if (eq[a] == j) { take = true; break; }
            if (take) {
                const int p = atomicAdd(&s_ns, 1);
                if (p < K) { selv[p] = v; seli[p] = j; }
            }
        }
        __syncthreads();
    }

    const int ns = s_ns < K ? s_ns : K;
    // index-rank sort winners (deterministic), pad tail with zeros
    if (t < K) { osi[t] = NS; osv[t] = 0.f; }   // inert defaults if ns < K
    __syncthreads();
    if (t < ns) {
        const int myi = seli[t];
        int r = 0;
        for (int j = 0; j < ns; ++j) r += (seli[j] < myi);
        osi[r] = myi;
        osv[r] = selv[t];
    }

    // full-row z write + scatter
    {
        const f32x4 z4 = {0.f, 0.f, 0.f, 0.f};
        f32x4* zw = (f32x4*)zr;
        for (int i = t; i < NS / 4; i += 256)
            __builtin_nontemporal_store(z4, &zw[i]);
    }
    __syncthreads();
    if (t < ns) __builtin_nontemporal_store(osv[t], &zr[osi[t]]);

    // in-block decode (osi[k]=NS entries contribute 0 via osv=0; guard the gather)
    if (t < 192) {
        const int d0 = t * 4;
        f32x4 a = *(const f32x4*)&bd[d0];
        for (int k = 0; k < K; ++k) {
            const int s = (osi[k] < NS) ? osi[k] : 0;
            const ushort4 wv = *(const ushort4*)(WTb + (size_t)s * DM + d0);
            const float v = osv[k];
            a.x = fmaf(v, bf2f(wv.x), a.x);
            a.y = fmaf(v, bf2f(wv.y), a.y);
            a.z = fmaf(v, bf2f(wv.z), a.z);
            a.w = fmaf(v, bf2f(wv.w), a.w);
        }
        __builtin_nontemporal_store(a, (f32x4*)&recon[(size_t)row * DM + d0]);
    }
}

// ===================== small-ws legacy path (round-1, validated) =====================
#define BM 128
#define BN 128
#define BK 16

__global__ __launch_bounds__(256) void encode_gemm(
    const float* __restrict__ x, const float* __restrict__ We,
    const float* __restrict__ be, const float* __restrict__ bp,
    float* __restrict__ z)
{
    __shared__ __align__(16) float As[BK][BM + 4];
    __shared__ __align__(16) float Bs[BK][BN + 4];

    const int t  = threadIdx.x;
    const int bm = blockIdx.y * BM;
    const int bn = blockIdx.x * BN;
    const int tm = (t / 16) * 8;
    const int tn = (t % 16) * 8;

    float acc[8][8] = {};

    for (int k0 = 0; k0 < DM; k0 += BK) {
        #pragma unroll
        for (int h = 0; h < 2; ++h) {
            const int q  = t + h * 256;
            const int m  = q >> 2;
            const int kq = (q & 3) * 4;
            const float4 av = *(const float4*)&x[(size_t)(bm + m) * DM + k0 + kq];
            const float4 pv = *(const float4*)&bp[k0 + kq];
            As[kq + 0][m] = av.x - pv.x;
            As[kq + 1][m] = av.y - pv.y;
            As[kq + 2][m] = av.z - pv.z;
            As[kq + 3][m] = av.w - pv.w;
            const float4 bv = *(const float4*)&We[(size_t)(bn + m) * DM + k0 + kq];
            Bs[kq + 0][m] = bv.x;
            Bs[kq + 1][m] = bv.y;
            Bs[kq + 2][m] = bv.z;
            Bs[kq + 3][m] = bv.w;
        }
        __syncthreads();

        #pragma unroll
        for (int kk = 0; kk < BK; ++kk) {
            float a[8], b[8];
            *(float4*)&a[0] = *(const float4*)&As[kk][tm];
            *(float4*)&a[4] = *(const float4*)&As[kk][tm + 4];
            *(float4*)&b[0] = *(const float4*)&Bs[kk][tn];
            *(float4*)&b[4] = *(const float4*)&Bs[kk][tn + 4];
            #pragma unroll
            for (int i = 0; i < 8; ++i)
                #pragma unroll
                for (int j = 0; j < 8; ++j)
                    acc[i][j] = fmaf(a[i], b[j], acc[i][j]);
        }
        __syncthreads();
    }

    float4 be0 = *(const float4*)&be[bn + tn];
    float4 be1 = *(const float4*)&be[bn + tn + 4];
    #pragma unroll
    for (int i = 0; i < 8; ++i) {
        const size_t rowoff = (size_t)(bm + tm + i) * NS + bn + tn;
        float4 c0, c1;
        c0.x = acc[i][0] + be0.x; c0.y = acc[i][1] + be0.y;
        c0.z = acc[i][2] + be0.z; c0.w = acc[i][3] + be0.w;
        c1.x = acc[i][4] + be1.x; c1.y = acc[i][5] + be1.y;
        c1.z = acc[i][6] + be1.z; c1.w = acc[i][7] + be1.w;
        *(float4*)&z[rowoff]     = c0;
        *(float4*)&z[rowoff + 4] = c1;
    }
}

__global__ __launch_bounds__(256) void topk_kernel(
    float* __restrict__ z, float* __restrict__ tv, int* __restrict__ ti)
{
    const int row = blockIdx.x;
    float* zr = z + (size_t)row * NS;
    const int t = threadIdx.x;

    __shared__ unsigned hist[256];
    __shared__ unsigned s_prefix, s_pmask;
    __shared__ int s_need;
    __shared__ int eqidx[128];
    __shared__ int eqcnt, outcnt;
    __shared__ float osv[K];
    __shared__ int   osi[K];

    if (t == 0) { s_prefix = 0u; s_pmask = 0u; s_need = K; eqcnt = 0; outcnt = 0; }
    __syncthreads();

    for (int shift = 24; shift >= 0; shift -= 8) {
        hist[t] = 0u;
        __syncthreads();
        const unsigned prefix = s_prefix, pmask = s_pmask;
        for (int i = t; i < NS; i += 256) {
            unsigned u = fkey(zr[i]);
            if ((u & pmask) == prefix) atomicAdd(&hist[(u >> shift) & 255u], 1u);
        }
        __syncthreads();
        if (t == 0) {
            int need = s_need;
            unsigned cum = 0; int sel = 0;
            for (int b = 255; b >= 0; --b) {
                if (cum + hist[b] >= (unsigned)need) { sel = b; break; }
                cum += hist[b];
            }
            s_need   = need - (int)cum;
            s_prefix = prefix | ((unsigned)sel << shift);
            s_pmask  = pmask | (0xFFu << shift);
        }
        __syncthreads();
    }

    const unsigned T = s_prefix;
    const int need = s_need;

    for (int i = t; i < NS; i += 256) {
        if (fkey(zr[i]) == T) {
            int p = atomicAdd(&eqcnt, 1);
            if (p < 128) eqidx[p] = i;
        }
    }
    __syncthreads();
    if (t == 0) {
        int nn = eqcnt < 128 ? eqcnt : 128;
        int lim = need < nn ? need : nn;
        for (int a = 0; a < lim; ++a) {
            int mi = a;
            for (int b = a + 1; b < nn; ++b) if (eqidx[b] < eqidx[mi]) mi = b;
            int tmp = eqidx[a]; eqidx[a] = eqidx[mi]; eqidx[mi] = tmp;
        }
    }
    __syncthreads();

    for (int i = t; i < NS; i += 256) {
        const float v = zr[i];
        const unsigned u = fkey(v);
        bool take = (u > T);
        if (u == T) {
            for (int a = 0; a < need; ++a) if (eqidx[a] == i) { take = true; break; }
        }
        if (take) {
            int p = atomicAdd(&outcnt, 1);
            if (p < K) { osv[p] = v; osi[p] = i; }
        } else {
            zr[i] = 0.0f;
        }
    }
    __syncthreads();

    if (tv != nullptr && t < K) {
        const int   myi = osi[t];
        const float myv = osv[t];
        int r = 0;
        #pragma unroll 8
        for (int j = 0; j < K; ++j) r += (osi[j] < myi);
        tv[(size_t)row * K + r] = myv;
        ti[(size_t)row * K + r] = myi;
    }
}

__global__ __launch_bounds__(256) void decode_nt(
    const float* __restrict__ tv, const int* __restrict__ ti,
    const float* __restrict__ Wd, const float* __restrict__ bd,
    float* __restrict__ recon)
{
    const int row = blockIdx.x;
    const int t = threadIdx.x;
    __shared__ float sv[K];
    __shared__ int   si[K];
    if (t < K) { sv[t] = tv[(size_t)row * K + t]; si[t] = ti[(size_t)row * K + t]; }
    __syncthreads();
    float a0 = bd[t], a1 = bd[t + 256], a2 = bd[t + 512];
    for (int k = 0; k < K; ++k) {
        const float v = sv[k];
        const int s = si[k];
        a0 = fmaf(v, Wd[(size_t)t * NS + s],         a0);
        a1 = fmaf(v, Wd[(size_t)(t + 256) * NS + s], a1);
        a2 = fmaf(v, Wd[(size_t)(t + 512) * NS + s], a2);
    }
    float* rr = recon + (size_t)row * DM;
    rr[t] = a0; rr[t + 256] = a1; rr[t + 512] = a2;
}

__global__ __launch_bounds__(256) void decode_scan(
    const float* __restrict__ z, const float* __restrict__ Wd,
    const float* __restrict__ bd, float* __restrict__ recon)
{
    constexpr int CAP2 = 96;
    const int row = blockIdx.x;
    const int t = threadIdx.x;
    __shared__ float sv[CAP2], sv2[CAP2];
    __shared__ int   si[CAP2], si2[CAP2];
    __shared__ int cnt;
    if (t == 0) cnt = 0;
    __syncthreads();
    const float* zr = z + (size_t)row * NS;
    for (int i = t; i < NS; i += 256) {
        float v = zr[i];
        if (v != 0.0f) { int p = atomicAdd(&cnt, 1); if (p < CAP2) { sv[p] = v; si[p] = i; } }
    }
    __syncthreads();
    const int n = cnt < CAP2 ? cnt : CAP2;
    if (t < n) {
        int myi = si[t]; int r = 0;
        for (int j = 0; j < n; ++j) r += (si[j] < myi);
        sv2[r] = sv[t]; si2[r] = myi;
    }
    __syncthreads();
    float a0 = bd[t], a1 = bd[t + 256], a2 = bd[t + 512];
    for (int k = 0; k < n; ++k) {
        const float v = sv2[k];
        const int s = si2[k];
        a0 = fmaf(v, Wd[(size_t)t * NS + s],         a0);
        a1 = fmaf(v, Wd[(size_t)(t + 256) * NS + s], a1);
        a2 = fmaf(v, Wd[(size_t)(t + 512) * NS + s], a2);
    }
    float* rr = recon + (size_t)row * DM;
    rr[t] = a0; rr[t + 256] = a1; rr[t + 512] = a2;
}

// ===================== launch =====================
extern "C" void kernel_launch(void* const* d_in, const int* in_sizes, int n_in,
                              void* d_out, int out_size, void* d_ws, size_t ws_size,
                              hipStream_t stream) {
    const float* x  = (const float*)d_in[0];
    const float* We = (const float*)d_in[1];
    const float* be = (const float*)d_in[2];
    const float* Wd = (const float*)d_in[3];
    const float* bd = (const float*)d_in[4];
    const float* bp = (const float*)d_in[5];

    float* recon = (float*)d_out;                       // [8192][768]
    float* zs    = recon + (size_t)NB * DM;             // [8192][24576] (z_sparse)

    const size_t szAh   = (size_t)NB * DM * 2;          // 12.6 MB
    const size_t szBh   = (size_t)NS * DM * 2;          // 37.7 MB
    const size_t szWTb  = (size_t)NS * DM * 2;          // 37.7 MB
    const size_t szCand = (size_t)NB * CAP * 8;         // 67.1 MB
    const size_t szCnt  = (size_t)NB * 4;               // 32 KB
    const size_t szFL   = (size_t)NB * 4;               // 32 KB
    const size_t need_fast = szAh + szBh + szWTb + szCand + szCnt + szFL;  // ~155 MB (r13-r15 proven)

    if (ws_size >= need_fast) {
        char* p = (char*)d_ws;
        short* Ah = (short*)p;                         p += szAh;
        short* Bh = (short*)p;                         p += szBh;
        unsigned short* WTb = (unsigned short*)p;      p += szWTb;
        unsigned long long* cand = (unsigned long long*)p;  p += szCand;
        int*   cnt = (int*)p;                          p += szCnt;
        int*   fl  = (int*)p;

        prep_all<<<PREP_BLKS + TR_BLKS + CNT_BLKS, 256, 0, stream>>>(x, bp, We, Ah, Bh, Wd, WTb, cnt);
        encode_filter<<<dim3(NS / 128, NB / 128), 256, 0, stream>>>(Ah, Bh, be, cand, cnt);
        topk_all<<<NB, 256, 0, stream>>>(cand, cnt, zs, x, bp, We, be, WTb, bd, recon, fl);
        topk_exact_fb<<<NB, 256, 0, stream>>>(zs, x, bp, We, be, WTb, bd, recon, fl);
    } else {
        const size_t szTV = (size_t)NB * K * 4;
        const size_t szTI = (size_t)NB * K * 4;
        const size_t need_small = szTV + szTI;
        float* tv = (float*)d_ws;
        int*   ti = (int*)((char*)d_ws + szTV);

        dim3 gg(NS / BN, NB / BM);
        encode_gemm<<<gg, 256, 0, stream>>>(x, We, be, bp, zs);

        if (ws_size >= need_small) {
            topk_kernel<<<NB, 256, 0, stream>>>(zs, tv, ti);
            decode_nt<<<NB, 256, 0, stream>>>(tv, ti, Wd, bd, recon);
        } else {
            topk_kernel<<<NB, 256, 0, stream>>>(zs, nullptr, nullptr);
            decode_scan<<<NB, 256, 0, stream>>>(zs, Wd, bd, recon);
        }
    }
}